// Round 14
// baseline (366.622 us; speedup 1.0000x reference)
//
#include <hip/hip_runtime.h>
#include <hip/hip_bf16.h>
#include <math.h>

#define N_NUC_C 100000
#define N_NN_C  1600000
#define EMB_C   128
#define MSG_C   32
#define OUT_C   128
#define NB1     98     // ceil(N_NUC / 1024) for the scan
#define NPART   8
#define R_PER_P (N_NUC_C / NPART)          // 12500 receivers per partition
#define SBLK    784                        // blocks per partition in scatter
#define STHREADS (SBLK * 256)              // 200704 threads per partition
#define LDS_USTR 17                        // uint row stride (16 packed + 1 pad)
#define NCH     32                         // edge chunks for histogram sort
#define CHUNK   (N_NN_C / NCH)             // 50000 edges per chunk
#define CH_ITERS ((CHUNK + 255) / 256)     // 196
#define HIST_BLOCKS (NCH * NPART)          // 256
#define PROJ_BLOCKS 1564                   // ceil(N_NUC/256) * 4

typedef __attribute__((ext_vector_type(8))) short bf16x8;
typedef __attribute__((ext_vector_type(4))) float f32x4;

__device__ __forceinline__ float silu_f(float y) {
    return y / (1.0f + __expf(-y));
}

// round-to-nearest-even f32->bf16, packed pair (a -> low 16, b -> high 16)
__device__ __forceinline__ unsigned pack_bf16x2(float a, float b) {
    unsigned ua = __float_as_uint(a); ua += 0x7FFFu + ((ua >> 16) & 1u);
    unsigned ub = __float_as_uint(b); ub += 0x7FFFu + ((ub >> 16) & 1u);
    return (ua >> 16) | (ub & 0xFFFF0000u);
}

__device__ __forceinline__ unsigned short bf16_of(float a) {
    unsigned ua = __float_as_uint(a); ua += 0x7FFFu + ((ua >> 16) & 1u);
    return (unsigned short)(ua >> 16);
}

// ---------------------------------------------------------------------------
// proj body (shared by combined and standalone kernels)
// ---------------------------------------------------------------------------
__device__ __forceinline__ void proj_body(
    int n, int pr, int c0,
    const float* __restrict__ s_embed, const float* __restrict__ r_embed,
    const float* __restrict__ W_s, const float* __restrict__ b_s,
    const float* __restrict__ W_r, const float* __restrict__ b_r,
    float* __restrict__ proj)
{
    const float* __restrict__ src = pr ? r_embed : s_embed;
    const float* __restrict__ W   = pr ? W_r : W_s;
    const float* __restrict__ b   = pr ? b_r : b_s;
    float* __restrict__ dst = proj + (size_t)pr * N_NUC_C * MSG_C;

    float acc[16];
    #pragma unroll
    for (int i = 0; i < 16; ++i) acc[i] = b[c0 + i];

    const float* row = src + (size_t)n * EMB_C;
    #pragma unroll 4
    for (int k = 0; k < EMB_C; k += 4) {
        const float4 rv = *reinterpret_cast<const float4*>(row + k);
        #pragma unroll
        for (int i = 0; i < 16; ++i) {
            acc[i] = fmaf(rv.x, W[(k + 0) * MSG_C + c0 + i], acc[i]);
            acc[i] = fmaf(rv.y, W[(k + 1) * MSG_C + c0 + i], acc[i]);
            acc[i] = fmaf(rv.z, W[(k + 2) * MSG_C + c0 + i], acc[i]);
            acc[i] = fmaf(rv.w, W[(k + 3) * MSG_C + c0 + i], acc[i]);
        }
    }

    float4* d = reinterpret_cast<float4*>(dst + (size_t)n * MSG_C + c0);
    d[0] = make_float4(acc[0],  acc[1],  acc[2],  acc[3]);
    d[1] = make_float4(acc[4],  acc[5],  acc[6],  acc[7]);
    d[2] = make_float4(acc[8],  acc[9],  acc[10], acc[11]);
    d[3] = make_float4(acc[12], acc[13], acc[14], acc[15]);
}

// ---------------------------------------------------------------------------
// Combined kernel: first HIST_BLOCKS do the atomic-free CSR histogram
// (block (c,p): LDS histogram of chunk c's receivers in partition p; lrank =
// LDS-atomic order; counts -> cnt2[c][r]); remaining blocks do projections.
// ZERO global atomics (replaces the 1.6M fabric-atomic rank pass, ~105 us).
// lrank lines are written byte-disjoint across partitions (safe).
// ---------------------------------------------------------------------------
__global__ __launch_bounds__(256) void proj_hist_kernel(
    const float* __restrict__ s_embed, const float* __restrict__ r_embed,
    const float* __restrict__ W_s, const float* __restrict__ b_s,
    const float* __restrict__ W_r, const float* __restrict__ b_r,
    float* __restrict__ proj,
    const int* __restrict__ receivers,
    int* __restrict__ lrank, int* __restrict__ cnt2 /* [NCH][N_NUC] */)
{
    __shared__ int cl[R_PER_P];   // 50 KB histogram
    const int bid = blockIdx.x;

    if (bid < HIST_BLOCKS) {
        const int c   = bid >> 3;
        const int p   = bid & 7;
        const int rlo = p * R_PER_P;

        for (int i = threadIdx.x; i < R_PER_P; i += 256) cl[i] = 0;
        __syncthreads();

        const int ebase = c * CHUNK;
        for (int it = 0; it < CH_ITERS; ++it) {
            const int el = it * 256 + threadIdx.x;
            if (el < CHUNK) {
                const int e = ebase + el;
                const int rr = receivers[e] - rlo;
                if ((unsigned)rr < (unsigned)R_PER_P)
                    lrank[e] = atomicAdd(&cl[rr], 1);
            }
        }
        __syncthreads();

        int* dst = cnt2 + (size_t)c * N_NUC_C + rlo;
        for (int i = threadIdx.x; i < R_PER_P; i += 256) dst[i] = cl[i];
        return;
    }

    const int pb  = bid - HIST_BLOCKS;       // 0..PROJ_BLOCKS-1
    const int sub = pb & 3;                  // {s,r} x {col half}
    const int n   = (pb >> 2) * 256 + threadIdx.x;
    if (n >= N_NUC_C) return;
    proj_body(n, sub >> 1, (sub & 1) * 16,
              s_embed, r_embed, W_s, b_s, W_r, b_r, proj);
}

// Standalone proj (fallback path)
__global__ __launch_bounds__(256) void proj_kernel(
    const float* __restrict__ s_embed, const float* __restrict__ r_embed,
    const float* __restrict__ W_s, const float* __restrict__ b_s,
    const float* __restrict__ W_r, const float* __restrict__ b_r,
    float* __restrict__ proj)
{
    const int n = blockIdx.x * blockDim.x + threadIdx.x;
    if (n >= N_NUC_C) return;
    const int sub = blockIdx.y;
    proj_body(n, sub >> 1, (sub & 1) * 16,
              s_embed, r_embed, W_s, b_s, W_r, b_r, proj);
}

// ---------------------------------------------------------------------------
// Per-receiver exclusive scan over the NCH chunks (in place) + total -> cnt.
// Coalesced within each chunk slice.
// ---------------------------------------------------------------------------
__global__ __launch_bounds__(256) void chunkscan_kernel(
    int* __restrict__ cnt2, int* __restrict__ cnt)
{
    const int r = blockIdx.x * 256 + threadIdx.x;
    if (r >= N_NUC_C) return;
    int s = 0;
    #pragma unroll
    for (int c = 0; c < NCH; ++c) {
        int* p = cnt2 + (size_t)c * N_NUC_C + r;
        const int t = *p;
        *p = s;
        s += t;
    }
    cnt[r] = s;
}

// Exclusive scan of cnt[N_NUC] -> offsets. Three tiny kernels.
__global__ __launch_bounds__(256) void scan1_kernel(
    const int* __restrict__ cnt, int* __restrict__ excl, int* __restrict__ blockTot)
{
    __shared__ int waveTot[4];
    const int t = threadIdx.x, b = blockIdx.x;
    const int lane = t & 63, wid = t >> 6;
    const int base = b * 1024 + t * 4;

    int d0 = (base + 0 < N_NUC_C) ? cnt[base + 0] : 0;
    int d1 = (base + 1 < N_NUC_C) ? cnt[base + 1] : 0;
    int d2 = (base + 2 < N_NUC_C) ? cnt[base + 2] : 0;
    int d3 = (base + 3 < N_NUC_C) ? cnt[base + 3] : 0;
    const int s = d0 + d1 + d2 + d3;

    int incl = s;
    #pragma unroll
    for (int off = 1; off < 64; off <<= 1) {
        int v = __shfl_up(incl, off);
        if (lane >= off) incl += v;
    }
    const int wexcl = incl - s;
    if (lane == 63) waveTot[wid] = incl;
    __syncthreads();
    int wbase = 0;
    for (int w = 0; w < wid; ++w) wbase += waveTot[w];
    const int e0 = wbase + wexcl;

    if (base + 0 < N_NUC_C) excl[base + 0] = e0;
    if (base + 1 < N_NUC_C) excl[base + 1] = e0 + d0;
    if (base + 2 < N_NUC_C) excl[base + 2] = e0 + d0 + d1;
    if (base + 3 < N_NUC_C) excl[base + 3] = e0 + d0 + d1 + d2;
    if (t == 255) blockTot[b] = wbase + incl;
}

__global__ __launch_bounds__(128) void scan2_kernel(
    const int* __restrict__ blockTot, int* __restrict__ blockOff)
{
    __shared__ int sh[128];
    const int t = threadIdx.x;
    const int v = (t < NB1) ? blockTot[t] : 0;
    sh[t] = v;
    __syncthreads();
    #pragma unroll
    for (int off = 1; off < 128; off <<= 1) {
        int x = 0;
        if (t >= off) x = sh[t - off];
        __syncthreads();
        sh[t] += x;
        __syncthreads();
    }
    if (t < NB1) blockOff[t] = sh[t] - v;
}

__global__ __launch_bounds__(256) void scan3_kernel(
    const int* __restrict__ excl, const int* __restrict__ blockOff,
    int* __restrict__ offsets)
{
    const int n = blockIdx.x * blockDim.x + threadIdx.x;
    if (n < N_NUC_C) offsets[n] = excl[n] + blockOff[n >> 10];
    if (n == 0) offsets[N_NUC_C] = N_NN_C;
}

// ---------------------------------------------------------------------------
// Partition-local ATOMIC-FREE scatter: dst = offsets[r] + chunkbase + lrank.
// cnt2[chunk][r] gathers hit a 50 KB L2-resident window per partition.
// ---------------------------------------------------------------------------
__global__ __launch_bounds__(256) void scatter_pack8_kernel(
    const int* __restrict__ senders, const int* __restrict__ receivers,
    const int* __restrict__ lrank, const int* __restrict__ cnt2,
    const int* __restrict__ offsets, int4* __restrict__ edge_pack)
{
    const int p    = blockIdx.x & 7;
    const int blk  = blockIdx.x >> 3;                 // 0..SBLK-1
    const int base = blk * 256 + threadIdx.x;         // 0..STHREADS-1
    const int rlo  = p * R_PER_P;
    const int rhi  = rlo + R_PER_P;

    #pragma unroll
    for (int k = 0; k < 8; ++k) {
        const int e = base + k * STHREADS;
        if (e < N_NN_C) {
            const int r = receivers[e];
            if (r >= rlo && r < rhi) {
                const int c   = e / CHUNK;
                const int dst = offsets[r] + cnt2[(size_t)c * N_NUC_C + r] + lrank[e];
                edge_pack[dst] = make_int4(e, senders[e], r, 0);
            }
        }
    }
}

// ---------------------------------------------------------------------------
// Fused CSR edge compute + in-block segmented reduction, gate via MFMA
// (R12/R13 structure, unchanged).
// ---------------------------------------------------------------------------
__global__ __launch_bounds__(256) void fused_csr_kernel(
    const float* __restrict__ proj,      // [2][N_NUC][MSG]
    const float* __restrict__ e_embed,   // [N_NN][MSG]
    const int4*  __restrict__ edge_pack, // [N_NN] (e, s, r, 0) CSR order
    const int*   __restrict__ offsets,   // [N_NUC+1]
    const float* __restrict__ ln_scale,
    const float* __restrict__ ln_bias,
    const float* __restrict__ W_e,       // [MSG][MSG]
    float*       __restrict__ msg)       // [N_NUC][MSG], pre-zeroed
{
    __shared__ unsigned lds_ev[256 * LDS_USTR];  // bf16 ev rows -> reused for msg staging
    __shared__ unsigned lds_g [256 * LDS_USTR];  // bf16 gate rows
    __shared__ int      lds_r[256];

    const int t    = threadIdx.x;
    const int lane = t & 63;
    const int wb   = t & ~63;            // wave's first row (0,64,128,192)
    const int B0   = blockIdx.x * 256;   // first CSR slot of this block

    const int4 pk = edge_pack[B0 + t];
    const int e = pk.x, s = pk.y, r = pk.z;
    lds_r[t] = r;

    // ---- stage own ev row to LDS as bf16 ----
    {
        const float4* ee = reinterpret_cast<const float4*>(e_embed + (size_t)e * MSG_C);
        unsigned* evrow = &lds_ev[t * LDS_USTR];
        #pragma unroll
        for (int q = 0; q < 8; ++q) {
            const float4 v = ee[q];
            evrow[2*q+0] = pack_bf16x2(v.x, v.y);
            evrow[2*q+1] = pack_bf16x2(v.z, v.w);
        }
    }

    // ---- B fragments of W_e (bf16): lane holds k=8*(lane>>4)+i, n=lane&15 ----
    bf16x8 bf0, bf1;
    {
        const int kg = (lane >> 4) * 8;
        const int n0 = lane & 15;
        #pragma unroll
        for (int i = 0; i < 8; ++i) {
            bf0[i] = (short)bf16_of(W_e[(kg + i) * MSG_C + n0]);
            bf1[i] = (short)bf16_of(W_e[(kg + i) * MSG_C + 16 + n0]);
        }
    }

    __syncthreads();   // B1: all ev rows staged

    // ---- MFMA: gate = ev @ W_e, write bf16 gate rows to LDS ----
    {
        unsigned short* g16 = reinterpret_cast<unsigned short*>(lds_g);
        #pragma unroll
        for (int mt = 0; mt < 4; ++mt) {
            const int arow = wb + mt * 16 + (lane & 15);
            const unsigned* ar = &lds_ev[arow * LDS_USTR + ((lane >> 4) << 2)];
            union { unsigned u[4]; bf16x8 v; } cvt;
            cvt.u[0] = ar[0]; cvt.u[1] = ar[1]; cvt.u[2] = ar[2]; cvt.u[3] = ar[3];
            const bf16x8 af = cvt.v;    // bf16 row already in operand order
            f32x4 z = {0.f, 0.f, 0.f, 0.f};
            const f32x4 a0 = __builtin_amdgcn_mfma_f32_16x16x32_bf16(af, bf0, z, 0, 0, 0);
            const f32x4 a1 = __builtin_amdgcn_mfma_f32_16x16x32_bf16(af, bf1, z, 0, 0, 0);
            const int rbase = wb + mt * 16 + ((lane >> 4) << 2);
            #pragma unroll
            for (int rg = 0; rg < 4; ++rg) {
                g16[(rbase + rg) * (2 * LDS_USTR) + (lane & 15)]      = bf16_of(a0[rg]);
                g16[(rbase + rg) * (2 * LDS_USTR) + 16 + (lane & 15)] = bf16_of(a1[rg]);
            }
        }
    }

    __syncthreads();   // B2: all gate rows written

    // ---- own gate row -> registers ----
    float g[MSG_C];
    {
        const unsigned* gr = &lds_g[t * LDS_USTR];
        #pragma unroll
        for (int j = 0; j < 16; ++j) {
            const unsigned u = gr[j];
            g[2*j]   = __uint_as_float(u << 16);
            g[2*j+1] = __uint_as_float(u & 0xFFFF0000u);
        }
    }

    // ---- x = proj_s + proj_r, LayerNorm + SiLU, msg -> lds_ev (reuse) ----
    const float4* ps = reinterpret_cast<const float4*>(proj + (size_t)s * MSG_C);
    const float4* pq = reinterpret_cast<const float4*>(proj + (size_t)(N_NUC_C + r) * MSG_C);
    float x[MSG_C];
    #pragma unroll
    for (int q = 0; q < 8; ++q) {
        const float4 a = ps[q];
        const float4 b = pq[q];
        x[4*q+0] = a.x + b.x; x[4*q+1] = a.y + b.y;
        x[4*q+2] = a.z + b.z; x[4*q+3] = a.w + b.w;
    }

    float mu = 0.0f;
    #pragma unroll
    for (int c = 0; c < MSG_C; ++c) mu += x[c];
    mu *= (1.0f / MSG_C);
    float var = 0.0f;
    #pragma unroll
    for (int c = 0; c < MSG_C; ++c) { const float d = x[c] - mu; var = fmaf(d, d, var); }
    var *= (1.0f / MSG_C);
    const float rs = rsqrtf(var + 1e-6f);

    unsigned* orow = &lds_ev[t * LDS_USTR];
    #pragma unroll
    for (int i = 0; i < 16; ++i) {
        const int c0_ = 2*i, c1_ = 2*i + 1;
        const float y0 = (x[c0_] - mu) * rs * ln_scale[c0_] + ln_bias[c0_];
        const float y1 = (x[c1_] - mu) * rs * ln_scale[c1_] + ln_bias[c1_];
        orow[i] = pack_bf16x2(silu_f(y0) * g[c0_], silu_f(y1) * g[c1_]);
    }

    __syncthreads();   // B3: all msg rows staged

    // ---- segmented reduction over receivers in this block ----
    const int r0 = lds_r[0];
    const int r1 = lds_r[255];
    const int total = (r1 - r0 + 1) << 5;   // (#receivers) * 32 channels

    for (int p = t; p < total; p += 256) {
        const int n  = r0 + (p >> 5);
        const int ch = p & 31;
        int b  = offsets[n];
        int en = offsets[n + 1];
        const bool interior = (b >= B0) && (en <= B0 + 256);
        if (b < B0) b = B0;
        if (en > B0 + 256) en = B0 + 256;

        const int dw  = ch >> 1;
        const bool hi = (ch & 1);
        float sum = 0.0f;
        for (int q = b - B0; q < en - B0; ++q) {
            const unsigned u = lds_ev[q * LDS_USTR + dw];
            sum += __uint_as_float(hi ? (u & 0xFFFF0000u) : (u << 16));
        }

        float* dst = msg + (size_t)n * MSG_C + ch;
        if (interior)       *dst = sum;          // sole owner (incl. empty = 0)
        else if (en > b)    atomicAdd(dst, sum); // straddling segment part
    }
}

// ---------------------------------------------------------------------------
// Fallback (tiny ws): R1 atomic edge kernel
// ---------------------------------------------------------------------------
__global__ __launch_bounds__(256) void edge_kernel(
    const float* __restrict__ proj, const float* __restrict__ e_embed,
    const int* __restrict__ senders, const int* __restrict__ receivers,
    const float* __restrict__ ln_scale, const float* __restrict__ ln_bias,
    const float* __restrict__ W_e, float* __restrict__ msg)
{
    const int e = blockIdx.x * blockDim.x + threadIdx.x;
    if (e >= N_NN_C) return;
    const int s = senders[e];
    const int r = receivers[e];
    const float4* ps = reinterpret_cast<const float4*>(proj + (size_t)s * MSG_C);
    const float4* pq = reinterpret_cast<const float4*>(proj + (size_t)(N_NUC_C + r) * MSG_C);
    float x[MSG_C];
    #pragma unroll
    for (int q = 0; q < 8; ++q) {
        const float4 a = ps[q];
        const float4 b = pq[q];
        x[4*q+0] = a.x + b.x; x[4*q+1] = a.y + b.y;
        x[4*q+2] = a.z + b.z; x[4*q+3] = a.w + b.w;
    }
    float mu = 0.0f;
    #pragma unroll
    for (int c = 0; c < MSG_C; ++c) mu += x[c];
    mu *= (1.0f / MSG_C);
    float var = 0.0f;
    #pragma unroll
    for (int c = 0; c < MSG_C; ++c) { const float d = x[c] - mu; var = fmaf(d, d, var); }
    var *= (1.0f / MSG_C);
    const float rs = rsqrtf(var + 1e-6f);
    #pragma unroll
    for (int c = 0; c < MSG_C; ++c) {
        const float y = (x[c] - mu) * rs * ln_scale[c] + ln_bias[c];
        x[c] = silu_f(y);
    }
    float ev[MSG_C];
    const float4* ee = reinterpret_cast<const float4*>(e_embed + (size_t)e * MSG_C);
    #pragma unroll
    for (int q = 0; q < 8; ++q) {
        const float4 v = ee[q];
        ev[4*q+0] = v.x; ev[4*q+1] = v.y; ev[4*q+2] = v.z; ev[4*q+3] = v.w;
    }
    float g[MSG_C];
    #pragma unroll
    for (int c = 0; c < MSG_C; ++c) g[c] = 0.0f;
    #pragma unroll
    for (int k = 0; k < MSG_C; ++k) {
        const float ek = ev[k];
        #pragma unroll
        for (int c = 0; c < MSG_C; ++c) g[c] = fmaf(ek, W_e[k * MSG_C + c], g[c]);
    }
    float* mrow = msg + (size_t)r * MSG_C;
    #pragma unroll
    for (int c = 0; c < MSG_C; ++c) atomicAdd(mrow + c, x[c] * g[c]);
}

// ---------------------------------------------------------------------------
// Kernel C: out[n][j] = silu( (msg[n] . W_out[:,j]) * norm[n] )
// ---------------------------------------------------------------------------
__global__ __launch_bounds__(256) void out_kernel(
    const float* __restrict__ msg, const float* __restrict__ norm,
    const float* __restrict__ W_out, float* __restrict__ out)
{
    const int j     = threadIdx.x & (OUT_C - 1);
    const int local = threadIdx.x >> 7;

    float w[MSG_C];
    #pragma unroll
    for (int k = 0; k < MSG_C; ++k) w[k] = W_out[k * OUT_C + j];

    for (int n = blockIdx.x * 2 + local; n < N_NUC_C; n += gridDim.x * 2) {
        const float4* m4 = reinterpret_cast<const float4*>(msg + (size_t)n * MSG_C);
        float acc = 0.0f;
        #pragma unroll
        for (int q = 0; q < 8; ++q) {
            const float4 mv = m4[q];
            acc = fmaf(mv.x, w[4*q+0], acc);
            acc = fmaf(mv.y, w[4*q+1], acc);
            acc = fmaf(mv.z, w[4*q+2], acc);
            acc = fmaf(mv.w, w[4*q+3], acc);
        }
        acc *= norm[n];
        out[(size_t)n * OUT_C + j] = silu_f(acc);
    }
}

extern "C" void kernel_launch(void* const* d_in, const int* in_sizes, int n_in,
                              void* d_out, int out_size, void* d_ws, size_t ws_size,
                              hipStream_t stream) {
    const float* s_embed   = (const float*)d_in[0];
    const float* r_embed   = (const float*)d_in[1];
    const float* e_embed   = (const float*)d_in[2];
    const float* norm      = (const float*)d_in[3];
    const int*   senders   = (const int*)d_in[4];
    const int*   receivers = (const int*)d_in[5];
    const float* W_s       = (const float*)d_in[6];
    const float* b_s       = (const float*)d_in[7];
    const float* W_r       = (const float*)d_in[8];
    const float* b_r       = (const float*)d_in[9];
    const float* ln_scale  = (const float*)d_in[10];
    const float* ln_bias   = (const float*)d_in[11];
    const float* W_e       = (const float*)d_in[12];
    const float* W_out     = (const float*)d_in[13];
    float* out = (float*)d_out;

    char* ws = (char*)d_ws;
    size_t off = 0;
    auto alloc = [&](size_t bytes) { char* p = ws + off; off += (bytes + 255) & ~(size_t)255; return p; };

    float* proj      = (float*)alloc((size_t)2 * N_NUC_C * MSG_C * 4); // 25.6 MB
    float* msg       = (float*)alloc((size_t)N_NUC_C * MSG_C * 4);     // 12.8 MB
    const size_t off_min = off;                                        // 38.4 MB
    int*   cnt       = (int*)  alloc((size_t)N_NUC_C * 4);
    int*   excl      = (int*)  alloc((size_t)N_NUC_C * 4);
    int*   offsets   = (int*)  alloc((size_t)(N_NUC_C + 1) * 4);
    int*   blockTot  = (int*)  alloc(128 * 4);
    int*   blockOff  = (int*)  alloc(128 * 4);
    int*   lrank     = (int*)  alloc((size_t)N_NN_C * 4);              // 6.4 MB
    int*   cnt2      = (int*)  alloc((size_t)NCH * N_NUC_C * 4);       // 12.8 MB
    int4*  edge_pack = (int4*) alloc((size_t)N_NN_C * 16);             // 25.6 MB
    const size_t off_full = off;                                       // ~85 MB

    if (off_full <= ws_size) {
        // --- [proj || LDS-histogram rank] (zero global atomics) + chunk scan
        //     + offsets scan + partition scatter + fused MFMA edge/reduce ---
        hipMemsetAsync(msg, 0, (size_t)N_NUC_C * MSG_C * 4, stream);
        proj_hist_kernel<<<HIST_BLOCKS + PROJ_BLOCKS, 256, 0, stream>>>(
            s_embed, r_embed, W_s, b_s, W_r, b_r, proj, receivers, lrank, cnt2);
        chunkscan_kernel<<<(N_NUC_C + 255) / 256, 256, 0, stream>>>(cnt2, cnt);
        scan1_kernel<<<NB1, 256, 0, stream>>>(cnt, excl, blockTot);
        scan2_kernel<<<1, 128, 0, stream>>>(blockTot, blockOff);
        scan3_kernel<<<(N_NUC_C + 255) / 256, 256, 0, stream>>>(excl, blockOff, offsets);
        scatter_pack8_kernel<<<NPART * SBLK, 256, 0, stream>>>(
            senders, receivers, lrank, cnt2, offsets, edge_pack);
        fused_csr_kernel<<<N_NN_C / 256, 256, 0, stream>>>(
            proj, e_embed, edge_pack, offsets, ln_scale, ln_bias, W_e, msg);
    } else if (off_min <= ws_size) {
        // --- fallback: R1 atomic path ---
        dim3 pgrid((N_NUC_C + 255) / 256, 4);
        proj_kernel<<<pgrid, 256, 0, stream>>>(s_embed, r_embed, W_s, b_s, W_r, b_r, proj);
        hipMemsetAsync(msg, 0, (size_t)N_NUC_C * MSG_C * 4, stream);
        edge_kernel<<<(N_NN_C + 255) / 256, 256, 0, stream>>>(
            proj, e_embed, senders, receivers, ln_scale, ln_bias, W_e, msg);
    }

    out_kernel<<<2048, 256, 0, stream>>>(msg, norm, W_out, out);
}

// Round 15
// 334.936 us; speedup vs baseline: 1.0946x; 1.0946x over previous
//
#include <hip/hip_runtime.h>
#include <hip/hip_bf16.h>
#include <math.h>

#define N_NUC_C 100000
#define N_NN_C  1600000
#define EMB_C   128
#define MSG_C   32
#define OUT_C   128
#define NB1     98     // ceil(N_NUC / 1024) for the scan
#define NPART   8
#define R_PER_P (N_NUC_C / NPART)          // 12500 receivers per partition
#define SBLK    784                        // blocks per partition in scatter
#define STHREADS (SBLK * 256)              // 200704 threads per partition
#define LDS_USTR 17                        // uint row stride (16 packed + 1 pad)
#define RANK_BLOCKS 6250                   // ceil(N_NN / 256)
#define PROJ_BLOCKS 1564                   // ceil(N_NUC/256) * 4

typedef __attribute__((ext_vector_type(8))) short bf16x8;
typedef __attribute__((ext_vector_type(4))) float f32x4;

__device__ __forceinline__ float silu_f(float y) {
    return y / (1.0f + __expf(-y));
}

// round-to-nearest-even f32->bf16, packed pair (a -> low 16, b -> high 16)
__device__ __forceinline__ unsigned pack_bf16x2(float a, float b) {
    unsigned ua = __float_as_uint(a); ua += 0x7FFFu + ((ua >> 16) & 1u);
    unsigned ub = __float_as_uint(b); ub += 0x7FFFu + ((ub >> 16) & 1u);
    return (ua >> 16) | (ub & 0xFFFF0000u);
}

__device__ __forceinline__ unsigned short bf16_of(float a) {
    unsigned ua = __float_as_uint(a); ua += 0x7FFFu + ((ua >> 16) & 1u);
    return (unsigned short)(ua >> 16);
}

// ---------------------------------------------------------------------------
// proj body (shared by combined and standalone kernels)
// ---------------------------------------------------------------------------
__device__ __forceinline__ void proj_body(
    int n, int pr, int c0,
    const float* __restrict__ s_embed, const float* __restrict__ r_embed,
    const float* __restrict__ W_s, const float* __restrict__ b_s,
    const float* __restrict__ W_r, const float* __restrict__ b_r,
    float* __restrict__ proj)
{
    const float* __restrict__ src = pr ? r_embed : s_embed;
    const float* __restrict__ W   = pr ? W_r : W_s;
    const float* __restrict__ b   = pr ? b_r : b_s;
    float* __restrict__ dst = proj + (size_t)pr * N_NUC_C * MSG_C;

    float acc[16];
    #pragma unroll
    for (int i = 0; i < 16; ++i) acc[i] = b[c0 + i];

    const float* row = src + (size_t)n * EMB_C;
    #pragma unroll 4
    for (int k = 0; k < EMB_C; k += 4) {
        const float4 rv = *reinterpret_cast<const float4*>(row + k);
        #pragma unroll
        for (int i = 0; i < 16; ++i) {
            acc[i] = fmaf(rv.x, W[(k + 0) * MSG_C + c0 + i], acc[i]);
            acc[i] = fmaf(rv.y, W[(k + 1) * MSG_C + c0 + i], acc[i]);
            acc[i] = fmaf(rv.z, W[(k + 2) * MSG_C + c0 + i], acc[i]);
            acc[i] = fmaf(rv.w, W[(k + 3) * MSG_C + c0 + i], acc[i]);
        }
    }

    float4* d = reinterpret_cast<float4*>(dst + (size_t)n * MSG_C + c0);
    d[0] = make_float4(acc[0],  acc[1],  acc[2],  acc[3]);
    d[1] = make_float4(acc[4],  acc[5],  acc[6],  acc[7]);
    d[2] = make_float4(acc[8],  acc[9],  acc[10], acc[11]);
    d[3] = make_float4(acc[12], acc[13], acc[14], acc[15]);
}

// ---------------------------------------------------------------------------
// Combined kernel (R13-proven): first RANK_BLOCKS do the CSR rank pass,
// remaining PROJ_BLOCKS do the projections (overlapped pipes).
// ---------------------------------------------------------------------------
__global__ __launch_bounds__(256) void proj_rank_kernel(
    const float* __restrict__ s_embed, const float* __restrict__ r_embed,
    const float* __restrict__ W_s, const float* __restrict__ b_s,
    const float* __restrict__ W_r, const float* __restrict__ b_r,
    float* __restrict__ proj,
    const int* __restrict__ receivers, int* __restrict__ cnt,
    int* __restrict__ rank)
{
    const int bid = blockIdx.x;
    if (bid < RANK_BLOCKS) {
        const int e = bid * 256 + threadIdx.x;
        if (e < N_NN_C) rank[e] = atomicAdd(&cnt[receivers[e]], 1);
        return;
    }
    const int pb  = bid - RANK_BLOCKS;       // 0..PROJ_BLOCKS-1
    const int sub = pb & 3;                  // {s,r} x {col half}
    const int n   = (pb >> 2) * 256 + threadIdx.x;
    if (n >= N_NUC_C) return;
    proj_body(n, sub >> 1, (sub & 1) * 16,
              s_embed, r_embed, W_s, b_s, W_r, b_r, proj);
}

// Standalone proj (fallback path)
__global__ __launch_bounds__(256) void proj_kernel(
    const float* __restrict__ s_embed, const float* __restrict__ r_embed,
    const float* __restrict__ W_s, const float* __restrict__ b_s,
    const float* __restrict__ W_r, const float* __restrict__ b_r,
    float* __restrict__ proj)
{
    const int n = blockIdx.x * blockDim.x + threadIdx.x;
    if (n >= N_NUC_C) return;
    const int sub = blockIdx.y;
    proj_body(n, sub >> 1, (sub & 1) * 16,
              s_embed, r_embed, W_s, b_s, W_r, b_r, proj);
}

// Exclusive scan of cnt[N_NUC] -> offsets. Three tiny kernels.
__global__ __launch_bounds__(256) void scan1_kernel(
    const int* __restrict__ cnt, int* __restrict__ excl, int* __restrict__ blockTot)
{
    __shared__ int waveTot[4];
    const int t = threadIdx.x, b = blockIdx.x;
    const int lane = t & 63, wid = t >> 6;
    const int base = b * 1024 + t * 4;

    int d0 = (base + 0 < N_NUC_C) ? cnt[base + 0] : 0;
    int d1 = (base + 1 < N_NUC_C) ? cnt[base + 1] : 0;
    int d2 = (base + 2 < N_NUC_C) ? cnt[base + 2] : 0;
    int d3 = (base + 3 < N_NUC_C) ? cnt[base + 3] : 0;
    const int s = d0 + d1 + d2 + d3;

    int incl = s;
    #pragma unroll
    for (int off = 1; off < 64; off <<= 1) {
        int v = __shfl_up(incl, off);
        if (lane >= off) incl += v;
    }
    const int wexcl = incl - s;
    if (lane == 63) waveTot[wid] = incl;
    __syncthreads();
    int wbase = 0;
    for (int w = 0; w < wid; ++w) wbase += waveTot[w];
    const int e0 = wbase + wexcl;

    if (base + 0 < N_NUC_C) excl[base + 0] = e0;
    if (base + 1 < N_NUC_C) excl[base + 1] = e0 + d0;
    if (base + 2 < N_NUC_C) excl[base + 2] = e0 + d0 + d1;
    if (base + 3 < N_NUC_C) excl[base + 3] = e0 + d0 + d1 + d2;
    if (t == 255) blockTot[b] = wbase + incl;
}

__global__ __launch_bounds__(128) void scan2_kernel(
    const int* __restrict__ blockTot, int* __restrict__ blockOff)
{
    __shared__ int sh[128];
    const int t = threadIdx.x;
    const int v = (t < NB1) ? blockTot[t] : 0;
    sh[t] = v;
    __syncthreads();
    #pragma unroll
    for (int off = 1; off < 128; off <<= 1) {
        int x = 0;
        if (t >= off) x = sh[t - off];
        __syncthreads();
        sh[t] += x;
        __syncthreads();
    }
    if (t < NB1) blockOff[t] = sh[t] - v;
}

__global__ __launch_bounds__(256) void scan3_kernel(
    const int* __restrict__ excl, const int* __restrict__ blockOff,
    int* __restrict__ offsets)
{
    const int n = blockIdx.x * blockDim.x + threadIdx.x;
    if (n < N_NUC_C) offsets[n] = excl[n] + blockOff[n >> 10];
    if (n == 0) offsets[N_NUC_C] = N_NN_C;
}

// ---------------------------------------------------------------------------
// Partition-local ATOMIC-FREE scatter (R7-proven).
// ---------------------------------------------------------------------------
__global__ __launch_bounds__(256) void scatter_pack8_kernel(
    const int* __restrict__ senders, const int* __restrict__ receivers,
    const int* __restrict__ rank, const int* __restrict__ offsets,
    int4* __restrict__ edge_pack)
{
    const int p    = blockIdx.x & 7;
    const int blk  = blockIdx.x >> 3;                 // 0..SBLK-1
    const int base = blk * 256 + threadIdx.x;         // 0..STHREADS-1
    const int rlo  = p * R_PER_P;
    const int rhi  = rlo + R_PER_P;

    #pragma unroll
    for (int k = 0; k < 8; ++k) {
        const int e = base + k * STHREADS;
        if (e < N_NN_C) {
            const int r = receivers[e];
            if (r >= rlo && r < rhi) {
                const int dst = offsets[r] + rank[e];
                edge_pack[dst] = make_int4(e, senders[e], r, 0);
            }
        }
    }
}

// ---------------------------------------------------------------------------
// Fused CSR edge compute + in-block segmented reduction, gate via MFMA.
// NEW vs R13: e_embed is gathered COOPERATIVELY (8 lanes per 128 B row,
// bf16-packed in flight into lds_ev) — 4x fewer L1 line-requests than the
// per-thread row loads (which re-request each 64 B line 4x). LDS unchanged.
// ---------------------------------------------------------------------------
__global__ __launch_bounds__(256) void fused_csr_kernel(
    const float* __restrict__ proj,      // [2][N_NUC][MSG]
    const float* __restrict__ e_embed,   // [N_NN][MSG]
    const int4*  __restrict__ edge_pack, // [N_NN] (e, s, r, 0) CSR order
    const int*   __restrict__ offsets,   // [N_NUC+1]
    const float* __restrict__ ln_scale,
    const float* __restrict__ ln_bias,
    const float* __restrict__ W_e,       // [MSG][MSG]
    float*       __restrict__ msg)       // [N_NUC][MSG], pre-zeroed
{
    __shared__ unsigned lds_ev[256 * LDS_USTR];  // bf16 ev rows -> reused for msg staging
    __shared__ unsigned lds_g [256 * LDS_USTR];  // bf16 gate rows
    __shared__ int      lds_r[256];
    __shared__ int      lds_e[256];

    const int t    = threadIdx.x;
    const int lane = t & 63;
    const int wb   = t & ~63;            // wave's first row (0,64,128,192)
    const int B0   = blockIdx.x * 256;   // first CSR slot of this block

    const int4 pk = edge_pack[B0 + t];
    const int e = pk.x, s = pk.y, r = pk.z;
    lds_r[t] = r;
    lds_e[t] = e;

    // ---- B fragments of W_e (bf16): lane holds k=8*(lane>>4)+i, n=lane&15 ----
    bf16x8 bf0, bf1;
    {
        const int kg = (lane >> 4) * 8;
        const int n0 = lane & 15;
        #pragma unroll
        for (int i = 0; i < 8; ++i) {
            bf0[i] = (short)bf16_of(W_e[(kg + i) * MSG_C + n0]);
            bf1[i] = (short)bf16_of(W_e[(kg + i) * MSG_C + 16 + n0]);
        }
    }

    __syncthreads();   // B0: lds_e ready

    // ---- cooperative e_embed gather: 8 lanes per row, bf16-pack in flight ----
    {
        const int rowb = t >> 3;          // 0..31 (32 rows per pass)
        const int sub  = t & 7;           // 16 B chunk within the row
        #pragma unroll
        for (int p = 0; p < 8; ++p) {
            const int i  = p * 32 + rowb;
            const int ei = lds_e[i];      // broadcast within 8-lane group
            const float4 v = *reinterpret_cast<const float4*>(
                e_embed + (size_t)ei * MSG_C + sub * 4);
            lds_ev[i * LDS_USTR + sub * 2 + 0] = pack_bf16x2(v.x, v.y);
            lds_ev[i * LDS_USTR + sub * 2 + 1] = pack_bf16x2(v.z, v.w);
        }
    }

    __syncthreads();   // B1: all ev rows staged

    // ---- MFMA: gate = ev @ W_e, write bf16 gate rows to LDS ----
    {
        unsigned short* g16 = reinterpret_cast<unsigned short*>(lds_g);
        #pragma unroll
        for (int mt = 0; mt < 4; ++mt) {
            const int arow = wb + mt * 16 + (lane & 15);
            const unsigned* ar = &lds_ev[arow * LDS_USTR + ((lane >> 4) << 2)];
            union { unsigned u[4]; bf16x8 v; } cvt;
            cvt.u[0] = ar[0]; cvt.u[1] = ar[1]; cvt.u[2] = ar[2]; cvt.u[3] = ar[3];
            const bf16x8 af = cvt.v;    // bf16 row already in operand order
            f32x4 z = {0.f, 0.f, 0.f, 0.f};
            const f32x4 a0 = __builtin_amdgcn_mfma_f32_16x16x32_bf16(af, bf0, z, 0, 0, 0);
            const f32x4 a1 = __builtin_amdgcn_mfma_f32_16x16x32_bf16(af, bf1, z, 0, 0, 0);
            const int rbase = wb + mt * 16 + ((lane >> 4) << 2);
            #pragma unroll
            for (int rg = 0; rg < 4; ++rg) {
                g16[(rbase + rg) * (2 * LDS_USTR) + (lane & 15)]      = bf16_of(a0[rg]);
                g16[(rbase + rg) * (2 * LDS_USTR) + 16 + (lane & 15)] = bf16_of(a1[rg]);
            }
        }
    }

    __syncthreads();   // B2: all gate rows written

    // ---- own gate row -> registers ----
    float g[MSG_C];
    {
        const unsigned* gr = &lds_g[t * LDS_USTR];
        #pragma unroll
        for (int j = 0; j < 16; ++j) {
            const unsigned u = gr[j];
            g[2*j]   = __uint_as_float(u << 16);
            g[2*j+1] = __uint_as_float(u & 0xFFFF0000u);
        }
    }

    // ---- x = proj_s + proj_r, LayerNorm + SiLU, msg -> lds_ev (reuse) ----
    const float4* ps = reinterpret_cast<const float4*>(proj + (size_t)s * MSG_C);
    const float4* pq = reinterpret_cast<const float4*>(proj + (size_t)(N_NUC_C + r) * MSG_C);
    float x[MSG_C];
    #pragma unroll
    for (int q = 0; q < 8; ++q) {
        const float4 a = ps[q];
        const float4 b = pq[q];
        x[4*q+0] = a.x + b.x; x[4*q+1] = a.y + b.y;
        x[4*q+2] = a.z + b.z; x[4*q+3] = a.w + b.w;
    }

    float mu = 0.0f;
    #pragma unroll
    for (int c = 0; c < MSG_C; ++c) mu += x[c];
    mu *= (1.0f / MSG_C);
    float var = 0.0f;
    #pragma unroll
    for (int c = 0; c < MSG_C; ++c) { const float d = x[c] - mu; var = fmaf(d, d, var); }
    var *= (1.0f / MSG_C);
    const float rs = rsqrtf(var + 1e-6f);

    unsigned* orow = &lds_ev[t * LDS_USTR];
    #pragma unroll
    for (int i = 0; i < 16; ++i) {
        const int c0_ = 2*i, c1_ = 2*i + 1;
        const float y0 = (x[c0_] - mu) * rs * ln_scale[c0_] + ln_bias[c0_];
        const float y1 = (x[c1_] - mu) * rs * ln_scale[c1_] + ln_bias[c1_];
        orow[i] = pack_bf16x2(silu_f(y0) * g[c0_], silu_f(y1) * g[c1_]);
    }

    __syncthreads();   // B3: all msg rows staged

    // ---- segmented reduction over receivers in this block ----
    const int r0 = lds_r[0];
    const int r1 = lds_r[255];
    const int total = (r1 - r0 + 1) << 5;   // (#receivers) * 32 channels

    for (int p = t; p < total; p += 256) {
        const int n  = r0 + (p >> 5);
        const int ch = p & 31;
        int b  = offsets[n];
        int en = offsets[n + 1];
        const bool interior = (b >= B0) && (en <= B0 + 256);
        if (b < B0) b = B0;
        if (en > B0 + 256) en = B0 + 256;

        const int dw  = ch >> 1;
        const bool hi = (ch & 1);
        float sum = 0.0f;
        for (int q = b - B0; q < en - B0; ++q) {
            const unsigned u = lds_ev[q * LDS_USTR + dw];
            sum += __uint_as_float(hi ? (u & 0xFFFF0000u) : (u << 16));
        }

        float* dst = msg + (size_t)n * MSG_C + ch;
        if (interior)       *dst = sum;          // sole owner (incl. empty = 0)
        else if (en > b)    atomicAdd(dst, sum); // straddling segment part
    }
}

// ---------------------------------------------------------------------------
// Fallback (tiny ws): R1 atomic edge kernel
// ---------------------------------------------------------------------------
__global__ __launch_bounds__(256) void edge_kernel(
    const float* __restrict__ proj, const float* __restrict__ e_embed,
    const int* __restrict__ senders, const int* __restrict__ receivers,
    const float* __restrict__ ln_scale, const float* __restrict__ ln_bias,
    const float* __restrict__ W_e, float* __restrict__ msg)
{
    const int e = blockIdx.x * blockDim.x + threadIdx.x;
    if (e >= N_NN_C) return;
    const int s = senders[e];
    const int r = receivers[e];
    const float4* ps = reinterpret_cast<const float4*>(proj + (size_t)s * MSG_C);
    const float4* pq = reinterpret_cast<const float4*>(proj + (size_t)(N_NUC_C + r) * MSG_C);
    float x[MSG_C];
    #pragma unroll
    for (int q = 0; q < 8; ++q) {
        const float4 a = ps[q];
        const float4 b = pq[q];
        x[4*q+0] = a.x + b.x; x[4*q+1] = a.y + b.y;
        x[4*q+2] = a.z + b.z; x[4*q+3] = a.w + b.w;
    }
    float mu = 0.0f;
    #pragma unroll
    for (int c = 0; c < MSG_C; ++c) mu += x[c];
    mu *= (1.0f / MSG_C);
    float var = 0.0f;
    #pragma unroll
    for (int c = 0; c < MSG_C; ++c) { const float d = x[c] - mu; var = fmaf(d, d, var); }
    var *= (1.0f / MSG_C);
    const float rs = rsqrtf(var + 1e-6f);
    #pragma unroll
    for (int c = 0; c < MSG_C; ++c) {
        const float y = (x[c] - mu) * rs * ln_scale[c] + ln_bias[c];
        x[c] = silu_f(y);
    }
    float ev[MSG_C];
    const float4* ee = reinterpret_cast<const float4*>(e_embed + (size_t)e * MSG_C);
    #pragma unroll
    for (int q = 0; q < 8; ++q) {
        const float4 v = ee[q];
        ev[4*q+0] = v.x; ev[4*q+1] = v.y; ev[4*q+2] = v.z; ev[4*q+3] = v.w;
    }
    float g[MSG_C];
    #pragma unroll
    for (int c = 0; c < MSG_C; ++c) g[c] = 0.0f;
    #pragma unroll
    for (int k = 0; k < MSG_C; ++k) {
        const float ek = ev[k];
        #pragma unroll
        for (int c = 0; c < MSG_C; ++c) g[c] = fmaf(ek, W_e[k * MSG_C + c], g[c]);
    }
    float* mrow = msg + (size_t)r * MSG_C;
    #pragma unroll
    for (int c = 0; c < MSG_C; ++c) atomicAdd(mrow + c, x[c] * g[c]);
}

// ---------------------------------------------------------------------------
// Kernel C: out[n][j] = silu( (msg[n] . W_out[:,j]) * norm[n] )
// ---------------------------------------------------------------------------
__global__ __launch_bounds__(256) void out_kernel(
    const float* __restrict__ msg, const float* __restrict__ norm,
    const float* __restrict__ W_out, float* __restrict__ out)
{
    const int j     = threadIdx.x & (OUT_C - 1);
    const int local = threadIdx.x >> 7;

    float w[MSG_C];
    #pragma unroll
    for (int k = 0; k < MSG_C; ++k) w[k] = W_out[k * OUT_C + j];

    for (int n = blockIdx.x * 2 + local; n < N_NUC_C; n += gridDim.x * 2) {
        const float4* m4 = reinterpret_cast<const float4*>(msg + (size_t)n * MSG_C);
        float acc = 0.0f;
        #pragma unroll
        for (int q = 0; q < 8; ++q) {
            const float4 mv = m4[q];
            acc = fmaf(mv.x, w[4*q+0], acc);
            acc = fmaf(mv.y, w[4*q+1], acc);
            acc = fmaf(mv.z, w[4*q+2], acc);
            acc = fmaf(mv.w, w[4*q+3], acc);
        }
        acc *= norm[n];
        out[(size_t)n * OUT_C + j] = silu_f(acc);
    }
}

extern "C" void kernel_launch(void* const* d_in, const int* in_sizes, int n_in,
                              void* d_out, int out_size, void* d_ws, size_t ws_size,
                              hipStream_t stream) {
    const float* s_embed   = (const float*)d_in[0];
    const float* r_embed   = (const float*)d_in[1];
    const float* e_embed   = (const float*)d_in[2];
    const float* norm      = (const float*)d_in[3];
    const int*   senders   = (const int*)d_in[4];
    const int*   receivers = (const int*)d_in[5];
    const float* W_s       = (const float*)d_in[6];
    const float* b_s       = (const float*)d_in[7];
    const float* W_r       = (const float*)d_in[8];
    const float* b_r       = (const float*)d_in[9];
    const float* ln_scale  = (const float*)d_in[10];
    const float* ln_bias   = (const float*)d_in[11];
    const float* W_e       = (const float*)d_in[12];
    const float* W_out     = (const float*)d_in[13];
    float* out = (float*)d_out;

    char* ws = (char*)d_ws;
    size_t off = 0;
    auto alloc = [&](size_t bytes) { char* p = ws + off; off += (bytes + 255) & ~(size_t)255; return p; };

    float* proj      = (float*)alloc((size_t)2 * N_NUC_C * MSG_C * 4); // 25.6 MB
    float* msg       = (float*)alloc((size_t)N_NUC_C * MSG_C * 4);     // 12.8 MB
    const size_t off_min = off;                                        // 38.4 MB
    int*   cnt       = (int*)  alloc((size_t)N_NUC_C * 4);
    int*   excl      = (int*)  alloc((size_t)N_NUC_C * 4);
    int*   offsets   = (int*)  alloc((size_t)(N_NUC_C + 1) * 4);
    int*   blockTot  = (int*)  alloc(128 * 4);
    int*   blockOff  = (int*)  alloc(128 * 4);
    int*   rank      = (int*)  alloc((size_t)N_NN_C * 4);              // 6.4 MB
    int4*  edge_pack = (int4*) alloc((size_t)N_NN_C * 16);             // 25.6 MB
    const size_t off_full = off;                                       // ~72 MB

    if (off_full <= ws_size) {
        // --- [proj || rank] combined + scan + partition scatter +
        //     fused MFMA edge/reduce with cooperative e_embed gather ---
        hipMemsetAsync(cnt, 0, (size_t)N_NUC_C * 4, stream);
        hipMemsetAsync(msg, 0, (size_t)N_NUC_C * MSG_C * 4, stream);
        proj_rank_kernel<<<RANK_BLOCKS + PROJ_BLOCKS, 256, 0, stream>>>(
            s_embed, r_embed, W_s, b_s, W_r, b_r, proj, receivers, cnt, rank);
        scan1_kernel<<<NB1, 256, 0, stream>>>(cnt, excl, blockTot);
        scan2_kernel<<<1, 128, 0, stream>>>(blockTot, blockOff);
        scan3_kernel<<<(N_NUC_C + 255) / 256, 256, 0, stream>>>(excl, blockOff, offsets);
        scatter_pack8_kernel<<<NPART * SBLK, 256, 0, stream>>>(
            senders, receivers, rank, offsets, edge_pack);
        fused_csr_kernel<<<N_NN_C / 256, 256, 0, stream>>>(
            proj, e_embed, edge_pack, offsets, ln_scale, ln_bias, W_e, msg);
    } else if (off_min <= ws_size) {
        // --- fallback: R1 atomic path ---
        dim3 pgrid((N_NUC_C + 255) / 256, 4);
        proj_kernel<<<pgrid, 256, 0, stream>>>(s_embed, r_embed, W_s, b_s, W_r, b_r, proj);
        hipMemsetAsync(msg, 0, (size_t)N_NUC_C * MSG_C * 4, stream);
        edge_kernel<<<(N_NN_C + 255) / 256, 256, 0, stream>>>(
            proj, e_embed, senders, receivers, ln_scale, ln_bias, W_e, msg);
    }

    out_kernel<<<2048, 256, 0, stream>>>(msg, norm, W_out, out);
}

// Round 16
// 304.016 us; speedup vs baseline: 1.2059x; 1.1017x over previous
//
#include <hip/hip_runtime.h>
#include <hip/hip_bf16.h>
#include <math.h>

#define N_NUC_C 100000
#define N_NN_C  1600000
#define EMB_C   128
#define MSG_C   32
#define OUT_C   128
#define NB1     98     // ceil(N_NUC / 1024) for the scan
#define NPART   8
#define R_PER_P (N_NUC_C / NPART)          // 12500 receivers per partition (scatter)
#define SBLK    784                        // blocks per partition in scatter
#define STHREADS (SBLK * 256)              // 200704 threads per partition
#define LDS_USTR 17                        // uint row stride (16 packed + 1 pad)
#define NCH2    256                        // chunks for histogram CSR build
#define CH2     (N_NN_C / NCH2)            // 6250 edges per chunk
#define CH2_IT  ((CH2 + 255) / 256)        // 25
#define HPART   2                          // receiver partitions in histogram
#define HR      (N_NUC_C / HPART)          // 50000 receivers per hist partition
#define HIST_BLOCKS (NCH2 * HPART)         // 512
#define PROJ_BLOCKS 1564                   // ceil(N_NUC/256) * 4

typedef __attribute__((ext_vector_type(8))) short bf16x8;
typedef __attribute__((ext_vector_type(4))) float f32x4;

__device__ __forceinline__ float silu_f(float y) {
    return y / (1.0f + __expf(-y));
}

// round-to-nearest-even f32->bf16, packed pair (a -> low 16, b -> high 16)
__device__ __forceinline__ unsigned pack_bf16x2(float a, float b) {
    unsigned ua = __float_as_uint(a); ua += 0x7FFFu + ((ua >> 16) & 1u);
    unsigned ub = __float_as_uint(b); ub += 0x7FFFu + ((ub >> 16) & 1u);
    return (ua >> 16) | (ub & 0xFFFF0000u);
}

__device__ __forceinline__ unsigned short bf16_of(float a) {
    unsigned ua = __float_as_uint(a); ua += 0x7FFFu + ((ua >> 16) & 1u);
    return (unsigned short)(ua >> 16);
}

// ---------------------------------------------------------------------------
// proj body (shared)
// ---------------------------------------------------------------------------
__device__ __forceinline__ void proj_body(
    int n, int pr, int c0,
    const float* __restrict__ s_embed, const float* __restrict__ r_embed,
    const float* __restrict__ W_s, const float* __restrict__ b_s,
    const float* __restrict__ W_r, const float* __restrict__ b_r,
    float* __restrict__ proj)
{
    const float* __restrict__ src = pr ? r_embed : s_embed;
    const float* __restrict__ W   = pr ? W_r : W_s;
    const float* __restrict__ b   = pr ? b_r : b_s;
    float* __restrict__ dst = proj + (size_t)pr * N_NUC_C * MSG_C;

    float acc[16];
    #pragma unroll
    for (int i = 0; i < 16; ++i) acc[i] = b[c0 + i];

    const float* row = src + (size_t)n * EMB_C;
    #pragma unroll 4
    for (int k = 0; k < EMB_C; k += 4) {
        const float4 rv = *reinterpret_cast<const float4*>(row + k);
        #pragma unroll
        for (int i = 0; i < 16; ++i) {
            acc[i] = fmaf(rv.x, W[(k + 0) * MSG_C + c0 + i], acc[i]);
            acc[i] = fmaf(rv.y, W[(k + 1) * MSG_C + c0 + i], acc[i]);
            acc[i] = fmaf(rv.z, W[(k + 2) * MSG_C + c0 + i], acc[i]);
            acc[i] = fmaf(rv.w, W[(k + 3) * MSG_C + c0 + i], acc[i]);
        }
    }

    float4* d = reinterpret_cast<float4*>(dst + (size_t)n * MSG_C + c0);
    d[0] = make_float4(acc[0],  acc[1],  acc[2],  acc[3]);
    d[1] = make_float4(acc[4],  acc[5],  acc[6],  acc[7]);
    d[2] = make_float4(acc[8],  acc[9],  acc[10], acc[11]);
    d[3] = make_float4(acc[12], acc[13], acc[14], acc[15]);
}

// ---------------------------------------------------------------------------
// Combined kernel: LDS-histogram CSR build (ZERO global atomics) + proj.
// Hist block (c,p): byte-packed LDS histogram (50 KB) of chunk c's receivers
// in partition p; lrank8[e] = old byte from LDS atomicAdd; counts -> cnt2
// (u8). 50% lane density, 2x redundant receiver reads (12.8 MB, trivial).
// Cross-block byte-disjoint line writes (lrank8/cnt2) merge safely.
// Counts fit u8: per-(chunk,receiver) <= ~8, degree <= ~60 (Poisson 16).
// ---------------------------------------------------------------------------
__global__ __launch_bounds__(256) void proj_hist2_kernel(
    const float* __restrict__ s_embed, const float* __restrict__ r_embed,
    const float* __restrict__ W_s, const float* __restrict__ b_s,
    const float* __restrict__ W_r, const float* __restrict__ b_r,
    float* __restrict__ proj,
    const int* __restrict__ receivers,
    unsigned char* __restrict__ lrank8,   // [N_NN]
    unsigned char* __restrict__ cnt2)     // [NCH2][N_NUC]
{
    __shared__ unsigned cl[HR / 4];   // 12500 uints = 50 KB, 4 byte-counters each
    const int bid = blockIdx.x;

    if (bid < HIST_BLOCKS) {
        const int c   = bid >> 1;
        const int p   = bid & 1;
        const int rlo = p * HR;

        for (int i = threadIdx.x; i < HR / 4; i += 256) cl[i] = 0;
        __syncthreads();

        const int ebase = c * CH2;
        #pragma unroll 1
        for (int it = 0; it < CH2_IT; ++it) {
            const int el = it * 256 + threadIdx.x;
            if (el < CH2) {
                const int e  = ebase + el;
                const int rr = receivers[e] - rlo;
                if ((unsigned)rr < (unsigned)HR) {
                    const int sh = (rr & 3) * 8;
                    const unsigned old = atomicAdd(&cl[rr >> 2], 1u << sh);
                    lrank8[e] = (unsigned char)((old >> sh) & 0xFFu);
                }
            }
        }
        __syncthreads();

        // dump 12500 uints (50000 bytes) to cnt2[c][rlo..rlo+HR)
        unsigned* dst = reinterpret_cast<unsigned*>(cnt2 + (size_t)c * N_NUC_C + rlo);
        for (int i = threadIdx.x; i < HR / 4; i += 256) dst[i] = cl[i];
        return;
    }

    const int pb  = bid - HIST_BLOCKS;       // 0..PROJ_BLOCKS-1
    const int sub = pb & 3;                  // {s,r} x {col half}
    const int n   = (pb >> 2) * 256 + threadIdx.x;
    if (n >= N_NUC_C) return;
    proj_body(n, sub >> 1, (sub & 1) * 16,
              s_embed, r_embed, W_s, b_s, W_r, b_r, proj);
}

// Standalone proj (fallback path)
__global__ __launch_bounds__(256) void proj_kernel(
    const float* __restrict__ s_embed, const float* __restrict__ r_embed,
    const float* __restrict__ W_s, const float* __restrict__ b_s,
    const float* __restrict__ W_r, const float* __restrict__ b_r,
    float* __restrict__ proj)
{
    const int n = blockIdx.x * blockDim.x + threadIdx.x;
    if (n >= N_NUC_C) return;
    const int sub = blockIdx.y;
    proj_body(n, sub >> 1, (sub & 1) * 16,
              s_embed, r_embed, W_s, b_s, W_r, b_r, proj);
}

// ---------------------------------------------------------------------------
// Per-receiver exclusive scan over NCH2 chunk counts (u8, in place) -> cnt.
// ---------------------------------------------------------------------------
__global__ __launch_bounds__(256) void chunkscan_kernel(
    unsigned char* __restrict__ cnt2, int* __restrict__ cnt)
{
    const int r = blockIdx.x * 256 + threadIdx.x;
    if (r >= N_NUC_C) return;
    int s = 0;
    #pragma unroll 8
    for (int c = 0; c < NCH2; ++c) {
        unsigned char* p = cnt2 + (size_t)c * N_NUC_C + r;
        const int t = *p;
        *p = (unsigned char)s;
        s += t;
    }
    cnt[r] = s;
}

// Exclusive scan of cnt[N_NUC] -> offsets. Three tiny kernels.
__global__ __launch_bounds__(256) void scan1_kernel(
    const int* __restrict__ cnt, int* __restrict__ excl, int* __restrict__ blockTot)
{
    __shared__ int waveTot[4];
    const int t = threadIdx.x, b = blockIdx.x;
    const int lane = t & 63, wid = t >> 6;
    const int base = b * 1024 + t * 4;

    int d0 = (base + 0 < N_NUC_C) ? cnt[base + 0] : 0;
    int d1 = (base + 1 < N_NUC_C) ? cnt[base + 1] : 0;
    int d2 = (base + 2 < N_NUC_C) ? cnt[base + 2] : 0;
    int d3 = (base + 3 < N_NUC_C) ? cnt[base + 3] : 0;
    const int s = d0 + d1 + d2 + d3;

    int incl = s;
    #pragma unroll
    for (int off = 1; off < 64; off <<= 1) {
        int v = __shfl_up(incl, off);
        if (lane >= off) incl += v;
    }
    const int wexcl = incl - s;
    if (lane == 63) waveTot[wid] = incl;
    __syncthreads();
    int wbase = 0;
    for (int w = 0; w < wid; ++w) wbase += waveTot[w];
    const int e0 = wbase + wexcl;

    if (base + 0 < N_NUC_C) excl[base + 0] = e0;
    if (base + 1 < N_NUC_C) excl[base + 1] = e0 + d0;
    if (base + 2 < N_NUC_C) excl[base + 2] = e0 + d0 + d1;
    if (base + 3 < N_NUC_C) excl[base + 3] = e0 + d0 + d1 + d2;
    if (t == 255) blockTot[b] = wbase + incl;
}

__global__ __launch_bounds__(128) void scan2_kernel(
    const int* __restrict__ blockTot, int* __restrict__ blockOff)
{
    __shared__ int sh[128];
    const int t = threadIdx.x;
    const int v = (t < NB1) ? blockTot[t] : 0;
    sh[t] = v;
    __syncthreads();
    #pragma unroll
    for (int off = 1; off < 128; off <<= 1) {
        int x = 0;
        if (t >= off) x = sh[t - off];
        __syncthreads();
        sh[t] += x;
        __syncthreads();
    }
    if (t < NB1) blockOff[t] = sh[t] - v;
}

__global__ __launch_bounds__(256) void scan3_kernel(
    const int* __restrict__ excl, const int* __restrict__ blockOff,
    int* __restrict__ offsets)
{
    const int n = blockIdx.x * blockDim.x + threadIdx.x;
    if (n < N_NUC_C) offsets[n] = excl[n] + blockOff[n >> 10];
    if (n == 0) offsets[N_NUC_C] = N_NN_C;
}

// ---------------------------------------------------------------------------
// Partition-local ATOMIC-FREE scatter:
// dst = offsets[r] + cnt2excl[chunk(e)][r] + lrank8[e].
// ---------------------------------------------------------------------------
__global__ __launch_bounds__(256) void scatter_pack8_kernel(
    const int* __restrict__ senders, const int* __restrict__ receivers,
    const unsigned char* __restrict__ lrank8,
    const unsigned char* __restrict__ cnt2,
    const int* __restrict__ offsets, int4* __restrict__ edge_pack)
{
    const int p    = blockIdx.x & 7;
    const int blk  = blockIdx.x >> 3;                 // 0..SBLK-1
    const int base = blk * 256 + threadIdx.x;         // 0..STHREADS-1
    const int rlo  = p * R_PER_P;
    const int rhi  = rlo + R_PER_P;

    #pragma unroll
    for (int k = 0; k < 8; ++k) {
        const int e = base + k * STHREADS;
        if (e < N_NN_C) {
            const int r = receivers[e];
            if (r >= rlo && r < rhi) {
                const int c   = e / CH2;
                const int dst = offsets[r] + (int)cnt2[(size_t)c * N_NUC_C + r]
                                          + (int)lrank8[e];
                edge_pack[dst] = make_int4(e, senders[e], r, 0);
            }
        }
    }
}

// ---------------------------------------------------------------------------
// Fused CSR edge compute + in-block segmented reduction, gate via MFMA,
// cooperative e_embed gather (R15-proven, unchanged).
// ---------------------------------------------------------------------------
__global__ __launch_bounds__(256) void fused_csr_kernel(
    const float* __restrict__ proj,      // [2][N_NUC][MSG]
    const float* __restrict__ e_embed,   // [N_NN][MSG]
    const int4*  __restrict__ edge_pack, // [N_NN] (e, s, r, 0) CSR order
    const int*   __restrict__ offsets,   // [N_NUC+1]
    const float* __restrict__ ln_scale,
    const float* __restrict__ ln_bias,
    const float* __restrict__ W_e,       // [MSG][MSG]
    float*       __restrict__ msg)       // [N_NUC][MSG], pre-zeroed
{
    __shared__ unsigned lds_ev[256 * LDS_USTR];  // bf16 ev rows -> reused for msg staging
    __shared__ unsigned lds_g [256 * LDS_USTR];  // bf16 gate rows
    __shared__ int      lds_r[256];
    __shared__ int      lds_e[256];

    const int t    = threadIdx.x;
    const int lane = t & 63;
    const int wb   = t & ~63;            // wave's first row (0,64,128,192)
    const int B0   = blockIdx.x * 256;   // first CSR slot of this block

    const int4 pk = edge_pack[B0 + t];
    const int e = pk.x, s = pk.y, r = pk.z;
    lds_r[t] = r;
    lds_e[t] = e;

    // ---- B fragments of W_e (bf16): lane holds k=8*(lane>>4)+i, n=lane&15 ----
    bf16x8 bf0, bf1;
    {
        const int kg = (lane >> 4) * 8;
        const int n0 = lane & 15;
        #pragma unroll
        for (int i = 0; i < 8; ++i) {
            bf0[i] = (short)bf16_of(W_e[(kg + i) * MSG_C + n0]);
            bf1[i] = (short)bf16_of(W_e[(kg + i) * MSG_C + 16 + n0]);
        }
    }

    __syncthreads();   // B0: lds_e ready

    // ---- cooperative e_embed gather: 8 lanes per row, bf16-pack in flight ----
    {
        const int rowb = t >> 3;          // 0..31 (32 rows per pass)
        const int sub  = t & 7;           // 16 B chunk within the row
        #pragma unroll
        for (int p = 0; p < 8; ++p) {
            const int i  = p * 32 + rowb;
            const int ei = lds_e[i];      // broadcast within 8-lane group
            const float4 v = *reinterpret_cast<const float4*>(
                e_embed + (size_t)ei * MSG_C + sub * 4);
            lds_ev[i * LDS_USTR + sub * 2 + 0] = pack_bf16x2(v.x, v.y);
            lds_ev[i * LDS_USTR + sub * 2 + 1] = pack_bf16x2(v.z, v.w);
        }
    }

    __syncthreads();   // B1: all ev rows staged

    // ---- MFMA: gate = ev @ W_e, write bf16 gate rows to LDS ----
    {
        unsigned short* g16 = reinterpret_cast<unsigned short*>(lds_g);
        #pragma unroll
        for (int mt = 0; mt < 4; ++mt) {
            const int arow = wb + mt * 16 + (lane & 15);
            const unsigned* ar = &lds_ev[arow * LDS_USTR + ((lane >> 4) << 2)];
            union { unsigned u[4]; bf16x8 v; } cvt;
            cvt.u[0] = ar[0]; cvt.u[1] = ar[1]; cvt.u[2] = ar[2]; cvt.u[3] = ar[3];
            const bf16x8 af = cvt.v;    // bf16 row already in operand order
            f32x4 z = {0.f, 0.f, 0.f, 0.f};
            const f32x4 a0 = __builtin_amdgcn_mfma_f32_16x16x32_bf16(af, bf0, z, 0, 0, 0);
            const f32x4 a1 = __builtin_amdgcn_mfma_f32_16x16x32_bf16(af, bf1, z, 0, 0, 0);
            const int rbase = wb + mt * 16 + ((lane >> 4) << 2);
            #pragma unroll
            for (int rg = 0; rg < 4; ++rg) {
                g16[(rbase + rg) * (2 * LDS_USTR) + (lane & 15)]      = bf16_of(a0[rg]);
                g16[(rbase + rg) * (2 * LDS_USTR) + 16 + (lane & 15)] = bf16_of(a1[rg]);
            }
        }
    }

    __syncthreads();   // B2: all gate rows written

    // ---- own gate row -> registers ----
    float g[MSG_C];
    {
        const unsigned* gr = &lds_g[t * LDS_USTR];
        #pragma unroll
        for (int j = 0; j < 16; ++j) {
            const unsigned u = gr[j];
            g[2*j]   = __uint_as_float(u << 16);
            g[2*j+1] = __uint_as_float(u & 0xFFFF0000u);
        }
    }

    // ---- x = proj_s + proj_r, LayerNorm + SiLU, msg -> lds_ev (reuse) ----
    const float4* ps = reinterpret_cast<const float4*>(proj + (size_t)s * MSG_C);
    const float4* pq = reinterpret_cast<const float4*>(proj + (size_t)(N_NUC_C + r) * MSG_C);
    float x[MSG_C];
    #pragma unroll
    for (int q = 0; q < 8; ++q) {
        const float4 a = ps[q];
        const float4 b = pq[q];
        x[4*q+0] = a.x + b.x; x[4*q+1] = a.y + b.y;
        x[4*q+2] = a.z + b.z; x[4*q+3] = a.w + b.w;
    }

    float mu = 0.0f;
    #pragma unroll
    for (int c = 0; c < MSG_C; ++c) mu += x[c];
    mu *= (1.0f / MSG_C);
    float var = 0.0f;
    #pragma unroll
    for (int c = 0; c < MSG_C; ++c) { const float d = x[c] - mu; var = fmaf(d, d, var); }
    var *= (1.0f / MSG_C);
    const float rs = rsqrtf(var + 1e-6f);

    unsigned* orow = &lds_ev[t * LDS_USTR];
    #pragma unroll
    for (int i = 0; i < 16; ++i) {
        const int c0_ = 2*i, c1_ = 2*i + 1;
        const float y0 = (x[c0_] - mu) * rs * ln_scale[c0_] + ln_bias[c0_];
        const float y1 = (x[c1_] - mu) * rs * ln_scale[c1_] + ln_bias[c1_];
        orow[i] = pack_bf16x2(silu_f(y0) * g[c0_], silu_f(y1) * g[c1_]);
    }

    __syncthreads();   // B3: all msg rows staged

    // ---- segmented reduction over receivers in this block ----
    const int r0 = lds_r[0];
    const int r1 = lds_r[255];
    const int total = (r1 - r0 + 1) << 5;   // (#receivers) * 32 channels

    for (int p = t; p < total; p += 256) {
        const int n  = r0 + (p >> 5);
        const int ch = p & 31;
        int b  = offsets[n];
        int en = offsets[n + 1];
        const bool interior = (b >= B0) && (en <= B0 + 256);
        if (b < B0) b = B0;
        if (en > B0 + 256) en = B0 + 256;

        const int dw  = ch >> 1;
        const bool hi = (ch & 1);
        float sum = 0.0f;
        for (int q = b - B0; q < en - B0; ++q) {
            const unsigned u = lds_ev[q * LDS_USTR + dw];
            sum += __uint_as_float(hi ? (u & 0xFFFF0000u) : (u << 16));
        }

        float* dst = msg + (size_t)n * MSG_C + ch;
        if (interior)       *dst = sum;          // sole owner (incl. empty = 0)
        else if (en > b)    atomicAdd(dst, sum); // straddling segment part
    }
}

// ---------------------------------------------------------------------------
// Fallback (tiny ws): R1 atomic edge kernel
// ---------------------------------------------------------------------------
__global__ __launch_bounds__(256) void edge_kernel(
    const float* __restrict__ proj, const float* __restrict__ e_embed,
    const int* __restrict__ senders, const int* __restrict__ receivers,
    const float* __restrict__ ln_scale, const float* __restrict__ ln_bias,
    const float* __restrict__ W_e, float* __restrict__ msg)
{
    const int e = blockIdx.x * blockDim.x + threadIdx.x;
    if (e >= N_NN_C) return;
    const int s = senders[e];
    const int r = receivers[e];
    const float4* ps = reinterpret_cast<const float4*>(proj + (size_t)s * MSG_C);
    const float4* pq = reinterpret_cast<const float4*>(proj + (size_t)(N_NUC_C + r) * MSG_C);
    float x[MSG_C];
    #pragma unroll
    for (int q = 0; q < 8; ++q) {
        const float4 a = ps[q];
        const float4 b = pq[q];
        x[4*q+0] = a.x + b.x; x[4*q+1] = a.y + b.y;
        x[4*q+2] = a.z + b.z; x[4*q+3] = a.w + b.w;
    }
    float mu = 0.0f;
    #pragma unroll
    for (int c = 0; c < MSG_C; ++c) mu += x[c];
    mu *= (1.0f / MSG_C);
    float var = 0.0f;
    #pragma unroll
    for (int c = 0; c < MSG_C; ++c) { const float d = x[c] - mu; var = fmaf(d, d, var); }
    var *= (1.0f / MSG_C);
    const float rs = rsqrtf(var + 1e-6f);
    #pragma unroll
    for (int c = 0; c < MSG_C; ++c) {
        const float y = (x[c] - mu) * rs * ln_scale[c] + ln_bias[c];
        x[c] = silu_f(y);
    }
    float ev[MSG_C];
    const float4* ee = reinterpret_cast<const float4*>(e_embed + (size_t)e * MSG_C);
    #pragma unroll
    for (int q = 0; q < 8; ++q) {
        const float4 v = ee[q];
        ev[4*q+0] = v.x; ev[4*q+1] = v.y; ev[4*q+2] = v.z; ev[4*q+3] = v.w;
    }
    float g[MSG_C];
    #pragma unroll
    for (int c = 0; c < MSG_C; ++c) g[c] = 0.0f;
    #pragma unroll
    for (int k = 0; k < MSG_C; ++k) {
        const float ek = ev[k];
        #pragma unroll
        for (int c = 0; c < MSG_C; ++c) g[c] = fmaf(ek, W_e[k * MSG_C + c], g[c]);
    }
    float* mrow = msg + (size_t)r * MSG_C;
    #pragma unroll
    for (int c = 0; c < MSG_C; ++c) atomicAdd(mrow + c, x[c] * g[c]);
}

// ---------------------------------------------------------------------------
// Kernel C: out[n][j] = silu( (msg[n] . W_out[:,j]) * norm[n] )
// ---------------------------------------------------------------------------
__global__ __launch_bounds__(256) void out_kernel(
    const float* __restrict__ msg, const float* __restrict__ norm,
    const float* __restrict__ W_out, float* __restrict__ out)
{
    const int j     = threadIdx.x & (OUT_C - 1);
    const int local = threadIdx.x >> 7;

    float w[MSG_C];
    #pragma unroll
    for (int k = 0; k < MSG_C; ++k) w[k] = W_out[k * OUT_C + j];

    for (int n = blockIdx.x * 2 + local; n < N_NUC_C; n += gridDim.x * 2) {
        const float4* m4 = reinterpret_cast<const float4*>(msg + (size_t)n * MSG_C);
        float acc = 0.0f;
        #pragma unroll
        for (int q = 0; q < 8; ++q) {
            const float4 mv = m4[q];
            acc = fmaf(mv.x, w[4*q+0], acc);
            acc = fmaf(mv.y, w[4*q+1], acc);
            acc = fmaf(mv.z, w[4*q+2], acc);
            acc = fmaf(mv.w, w[4*q+3], acc);
        }
        acc *= norm[n];
        out[(size_t)n * OUT_C + j] = silu_f(acc);
    }
}

extern "C" void kernel_launch(void* const* d_in, const int* in_sizes, int n_in,
                              void* d_out, int out_size, void* d_ws, size_t ws_size,
                              hipStream_t stream) {
    const float* s_embed   = (const float*)d_in[0];
    const float* r_embed   = (const float*)d_in[1];
    const float* e_embed   = (const float*)d_in[2];
    const float* norm      = (const float*)d_in[3];
    const int*   senders   = (const int*)d_in[4];
    const int*   receivers = (const int*)d_in[5];
    const float* W_s       = (const float*)d_in[6];
    const float* b_s       = (const float*)d_in[7];
    const float* W_r       = (const float*)d_in[8];
    const float* b_r       = (const float*)d_in[9];
    const float* ln_scale  = (const float*)d_in[10];
    const float* ln_bias   = (const float*)d_in[11];
    const float* W_e       = (const float*)d_in[12];
    const float* W_out     = (const float*)d_in[13];
    float* out = (float*)d_out;

    char* ws = (char*)d_ws;
    size_t off = 0;
    auto alloc = [&](size_t bytes) { char* p = ws + off; off += (bytes + 255) & ~(size_t)255; return p; };

    float* proj      = (float*)alloc((size_t)2 * N_NUC_C * MSG_C * 4); // 25.6 MB
    float* msg       = (float*)alloc((size_t)N_NUC_C * MSG_C * 4);     // 12.8 MB
    const size_t off_min = off;                                        // 38.4 MB
    int*   cnt       = (int*)  alloc((size_t)N_NUC_C * 4);
    int*   excl      = (int*)  alloc((size_t)N_NUC_C * 4);
    int*   offsets   = (int*)  alloc((size_t)(N_NUC_C + 1) * 4);
    int*   blockTot  = (int*)  alloc(128 * 4);
    int*   blockOff  = (int*)  alloc(128 * 4);
    unsigned char* lrank8 = (unsigned char*)alloc((size_t)N_NN_C);     // 1.6 MB
    unsigned char* cnt2   = (unsigned char*)alloc((size_t)NCH2 * N_NUC_C); // 25.6 MB
    int4*  edge_pack = (int4*) alloc((size_t)N_NN_C * 16);             // 25.6 MB
    const size_t off_full = off;                                       // ~92 MB

    if (off_full <= ws_size) {
        // --- [proj || LDS-hist CSR build] (zero global atomics) + chunkscan
        //     + offsets scan + partition scatter + fused MFMA edge/reduce ---
        hipMemsetAsync(msg, 0, (size_t)N_NUC_C * MSG_C * 4, stream);
        proj_hist2_kernel<<<HIST_BLOCKS + PROJ_BLOCKS, 256, 0, stream>>>(
            s_embed, r_embed, W_s, b_s, W_r, b_r, proj, receivers, lrank8, cnt2);
        chunkscan_kernel<<<(N_NUC_C + 255) / 256, 256, 0, stream>>>(cnt2, cnt);
        scan1_kernel<<<NB1, 256, 0, stream>>>(cnt, excl, blockTot);
        scan2_kernel<<<1, 128, 0, stream>>>(blockTot, blockOff);
        scan3_kernel<<<(N_NUC_C + 255) / 256, 256, 0, stream>>>(excl, blockOff, offsets);
        scatter_pack8_kernel<<<NPART * SBLK, 256, 0, stream>>>(
            senders, receivers, lrank8, cnt2, offsets, edge_pack);
        fused_csr_kernel<<<N_NN_C / 256, 256, 0, stream>>>(
            proj, e_embed, edge_pack, offsets, ln_scale, ln_bias, W_e, msg);
    } else if (off_min <= ws_size) {
        // --- fallback: R1 atomic path ---
        dim3 pgrid((N_NUC_C + 255) / 256, 4);
        proj_kernel<<<pgrid, 256, 0, stream>>>(s_embed, r_embed, W_s, b_s, W_r, b_r, proj);
        hipMemsetAsync(msg, 0, (size_t)N_NUC_C * MSG_C * 4, stream);
        edge_kernel<<<(N_NN_C + 255) / 256, 256, 0, stream>>>(
            proj, e_embed, senders, receivers, ln_scale, ln_bias, W_e, msg);
    }

    out_kernel<<<2048, 256, 0, stream>>>(msg, norm, W_out, out);
}

// Round 18
// 302.432 us; speedup vs baseline: 1.2122x; 1.0052x over previous
//
#include <hip/hip_runtime.h>
#include <hip/hip_bf16.h>
#include <math.h>

#define N_NUC_C 100000
#define N_NN_C  1600000
#define EMB_C   128
#define MSG_C   32
#define OUT_C   128
#define NB1     98     // ceil(N_NUC / 1024) for the scan
#define NPART   4
#define R_PER_P (N_NUC_C / NPART)          // 25000 receivers per partition (scatter)
#define SBLK    1568                       // blocks per partition in scatter
#define STHREADS (SBLK * 256)              // 401408 threads per partition
#define LDS_USTR 17                        // uint row stride (16 packed + 1 pad)
#define NCH2    256                        // chunks for histogram CSR build
#define CH2     (N_NN_C / NCH2)            // 6250 edges per chunk
#define CH2_IT  ((CH2 + 255) / 256)        // 25
#define HPART   2                          // receiver partitions in histogram
#define HR      (N_NUC_C / HPART)          // 50000 receivers per hist partition
#define HIST_BLOCKS (NCH2 * HPART)         // 512
#define PROJ_BLOCKS 1564                   // ceil(N_NUC/256) * 4
#define MSG_F4  (N_NUC_C * MSG_C / 4)      // 800000 float4s in msg

typedef __attribute__((ext_vector_type(8))) short bf16x8;
typedef __attribute__((ext_vector_type(4))) float f32x4;

__device__ __forceinline__ float silu_f(float y) {
    return y / (1.0f + __expf(-y));
}

// round-to-nearest-even f32->bf16, packed pair (a -> low 16, b -> high 16)
__device__ __forceinline__ unsigned pack_bf16x2(float a, float b) {
    unsigned ua = __float_as_uint(a); ua += 0x7FFFu + ((ua >> 16) & 1u);
    unsigned ub = __float_as_uint(b); ub += 0x7FFFu + ((ub >> 16) & 1u);
    return (ua >> 16) | (ub & 0xFFFF0000u);
}

__device__ __forceinline__ unsigned short bf16_of(float a) {
    unsigned ua = __float_as_uint(a); ua += 0x7FFFu + ((ua >> 16) & 1u);
    return (unsigned short)(ua >> 16);
}

// ---------------------------------------------------------------------------
// Fast msg zeroing (ROCm's fillBuffer runs at ~110 GB/s for this size; a
// proper grid-stride store hits stream rate -> ~4 us instead of ~115 us).
// ---------------------------------------------------------------------------
__global__ __launch_bounds__(256) void zero_msg_kernel(float4* __restrict__ msg4)
{
    const int i = blockIdx.x * 256 + threadIdx.x;
    if (i < MSG_F4) msg4[i] = make_float4(0.f, 0.f, 0.f, 0.f);
}

// ---------------------------------------------------------------------------
// proj body (shared)
// ---------------------------------------------------------------------------
__device__ __forceinline__ void proj_body(
    int n, int pr, int c0,
    const float* __restrict__ s_embed, const float* __restrict__ r_embed,
    const float* __restrict__ W_s, const float* __restrict__ b_s,
    const float* __restrict__ W_r, const float* __restrict__ b_r,
    float* __restrict__ proj)
{
    const float* __restrict__ src = pr ? r_embed : s_embed;
    const float* __restrict__ W   = pr ? W_r : W_s;
    const float* __restrict__ b   = pr ? b_r : b_s;
    float* __restrict__ dst = proj + (size_t)pr * N_NUC_C * MSG_C;

    float acc[16];
    #pragma unroll
    for (int i = 0; i < 16; ++i) acc[i] = b[c0 + i];

    const float* row = src + (size_t)n * EMB_C;
    #pragma unroll 4
    for (int k = 0; k < EMB_C; k += 4) {
        const float4 rv = *reinterpret_cast<const float4*>(row + k);
        #pragma unroll
        for (int i = 0; i < 16; ++i) {
            acc[i] = fmaf(rv.x, W[(k + 0) * MSG_C + c0 + i], acc[i]);
            acc[i] = fmaf(rv.y, W[(k + 1) * MSG_C + c0 + i], acc[i]);
            acc[i] = fmaf(rv.z, W[(k + 2) * MSG_C + c0 + i], acc[i]);
            acc[i] = fmaf(rv.w, W[(k + 3) * MSG_C + c0 + i], acc[i]);
        }
    }

    float4* d = reinterpret_cast<float4*>(dst + (size_t)n * MSG_C + c0);
    d[0] = make_float4(acc[0],  acc[1],  acc[2],  acc[3]);
    d[1] = make_float4(acc[4],  acc[5],  acc[6],  acc[7]);
    d[2] = make_float4(acc[8],  acc[9],  acc[10], acc[11]);
    d[3] = make_float4(acc[12], acc[13], acc[14], acc[15]);
}

// ---------------------------------------------------------------------------
// Combined kernel: LDS-histogram CSR build (ZERO global atomics) + proj.
// (R16-proven.)
// ---------------------------------------------------------------------------
__global__ __launch_bounds__(256) void proj_hist2_kernel(
    const float* __restrict__ s_embed, const float* __restrict__ r_embed,
    const float* __restrict__ W_s, const float* __restrict__ b_s,
    const float* __restrict__ W_r, const float* __restrict__ b_r,
    float* __restrict__ proj,
    const int* __restrict__ receivers,
    unsigned char* __restrict__ lrank8,   // [N_NN]
    unsigned char* __restrict__ cnt2)     // [NCH2][N_NUC]
{
    __shared__ unsigned cl[HR / 4];   // 12500 uints = 50 KB, 4 byte-counters each
    const int bid = blockIdx.x;

    if (bid < HIST_BLOCKS) {
        const int c   = bid >> 1;
        const int p   = bid & 1;
        const int rlo = p * HR;

        for (int i = threadIdx.x; i < HR / 4; i += 256) cl[i] = 0;
        __syncthreads();

        const int ebase = c * CH2;
        #pragma unroll 1
        for (int it = 0; it < CH2_IT; ++it) {
            const int el = it * 256 + threadIdx.x;
            if (el < CH2) {
                const int e  = ebase + el;
                const int rr = receivers[e] - rlo;
                if ((unsigned)rr < (unsigned)HR) {
                    const int sh = (rr & 3) * 8;
                    const unsigned old = atomicAdd(&cl[rr >> 2], 1u << sh);
                    lrank8[e] = (unsigned char)((old >> sh) & 0xFFu);
                }
            }
        }
        __syncthreads();

        unsigned* dst = reinterpret_cast<unsigned*>(cnt2 + (size_t)c * N_NUC_C + rlo);
        for (int i = threadIdx.x; i < HR / 4; i += 256) dst[i] = cl[i];
        return;
    }

    const int pb  = bid - HIST_BLOCKS;       // 0..PROJ_BLOCKS-1
    const int sub = pb & 3;                  // {s,r} x {col half}
    const int n   = (pb >> 2) * 256 + threadIdx.x;
    if (n >= N_NUC_C) return;
    proj_body(n, sub >> 1, (sub & 1) * 16,
              s_embed, r_embed, W_s, b_s, W_r, b_r, proj);
}

// Standalone proj (fallback path)
__global__ __launch_bounds__(256) void proj_kernel(
    const float* __restrict__ s_embed, const float* __restrict__ r_embed,
    const float* __restrict__ W_s, const float* __restrict__ b_s,
    const float* __restrict__ W_r, const float* __restrict__ b_r,
    float* __restrict__ proj)
{
    const int n = blockIdx.x * blockDim.x + threadIdx.x;
    if (n >= N_NUC_C) return;
    const int sub = blockIdx.y;
    proj_body(n, sub >> 1, (sub & 1) * 16,
              s_embed, r_embed, W_s, b_s, W_r, b_r, proj);
}

// ---------------------------------------------------------------------------
// Per-receiver exclusive scan over NCH2 chunk counts (u8, in place) -> cnt.
// ---------------------------------------------------------------------------
__global__ __launch_bounds__(256) void chunkscan_kernel(
    unsigned char* __restrict__ cnt2, int* __restrict__ cnt)
{
    const int r = blockIdx.x * 256 + threadIdx.x;
    if (r >= N_NUC_C) return;
    int s = 0;
    #pragma unroll 8
    for (int c = 0; c < NCH2; ++c) {
        unsigned char* p = cnt2 + (size_t)c * N_NUC_C + r;
        const int t = *p;
        *p = (unsigned char)s;
        s += t;
    }
    cnt[r] = s;
}

// Exclusive scan of cnt[N_NUC] -> offsets. Three tiny kernels.
__global__ __launch_bounds__(256) void scan1_kernel(
    const int* __restrict__ cnt, int* __restrict__ excl, int* __restrict__ blockTot)
{
    __shared__ int waveTot[4];
    const int t = threadIdx.x, b = blockIdx.x;
    const int lane = t & 63, wid = t >> 6;
    const int base = b * 1024 + t * 4;

    int d0 = (base + 0 < N_NUC_C) ? cnt[base + 0] : 0;
    int d1 = (base + 1 < N_NUC_C) ? cnt[base + 1] : 0;
    int d2 = (base + 2 < N_NUC_C) ? cnt[base + 2] : 0;
    int d3 = (base + 3 < N_NUC_C) ? cnt[base + 3] : 0;
    const int s = d0 + d1 + d2 + d3;

    int incl = s;
    #pragma unroll
    for (int off = 1; off < 64; off <<= 1) {
        int v = __shfl_up(incl, off);
        if (lane >= off) incl += v;
    }
    const int wexcl = incl - s;
    if (lane == 63) waveTot[wid] = incl;
    __syncthreads();
    int wbase = 0;
    for (int w = 0; w < wid; ++w) wbase += waveTot[w];
    const int e0 = wbase + wexcl;

    if (base + 0 < N_NUC_C) excl[base + 0] = e0;
    if (base + 1 < N_NUC_C) excl[base + 1] = e0 + d0;
    if (base + 2 < N_NUC_C) excl[base + 2] = e0 + d0 + d1;
    if (base + 3 < N_NUC_C) excl[base + 3] = e0 + d0 + d1 + d2;
    if (t == 255) blockTot[b] = wbase + incl;
}

__global__ __launch_bounds__(128) void scan2_kernel(
    const int* __restrict__ blockTot, int* __restrict__ blockOff)
{
    __shared__ int sh[128];
    const int t = threadIdx.x;
    const int v = (t < NB1) ? blockTot[t] : 0;
    sh[t] = v;
    __syncthreads();
    #pragma unroll
    for (int off = 1; off < 128; off <<= 1) {
        int x = 0;
        if (t >= off) x = sh[t - off];
        __syncthreads();
        sh[t] += x;
        __syncthreads();
    }
    if (t < NB1) blockOff[t] = sh[t] - v;
}

__global__ __launch_bounds__(256) void scan3_kernel(
    const int* __restrict__ excl, const int* __restrict__ blockOff,
    int* __restrict__ offsets)
{
    const int n = blockIdx.x * blockDim.x + threadIdx.x;
    if (n < N_NUC_C) offsets[n] = excl[n] + blockOff[n >> 10];
    if (n == 0) offsets[N_NUC_C] = N_NN_C;
}

// ---------------------------------------------------------------------------
// Partition-local ATOMIC-FREE scatter (4 partitions):
// dst = offsets[r] + cnt2excl[chunk(e)][r] + lrank8[e].
// ---------------------------------------------------------------------------
__global__ __launch_bounds__(256) void scatter_pack8_kernel(
    const int* __restrict__ senders, const int* __restrict__ receivers,
    const unsigned char* __restrict__ lrank8,
    const unsigned char* __restrict__ cnt2,
    const int* __restrict__ offsets, int4* __restrict__ edge_pack)
{
    const int p    = blockIdx.x & (NPART - 1);
    const int blk  = blockIdx.x / NPART;              // 0..SBLK-1
    const int base = blk * 256 + threadIdx.x;         // 0..STHREADS-1
    const int rlo  = p * R_PER_P;
    const int rhi  = rlo + R_PER_P;

    #pragma unroll
    for (int k = 0; k < NPART; ++k) {
        const int e = base + k * STHREADS;
        if (e < N_NN_C) {
            const int r = receivers[e];
            if (r >= rlo && r < rhi) {
                const int c   = e / CH2;
                const int dst = offsets[r] + (int)cnt2[(size_t)c * N_NUC_C + r]
                                          + (int)lrank8[e];
                edge_pack[dst] = make_int4(e, senders[e], r, 0);
            }
        }
    }
}

// ---------------------------------------------------------------------------
// Fused CSR edge compute + in-block segmented reduction, gate via MFMA,
// cooperative e_embed gather (R15/R16-proven; msg pre-zeroed by zero_msg).
// ---------------------------------------------------------------------------
__global__ __launch_bounds__(256) void fused_csr_kernel(
    const float* __restrict__ proj,      // [2][N_NUC][MSG]
    const float* __restrict__ e_embed,   // [N_NN][MSG]
    const int4*  __restrict__ edge_pack, // [N_NN] (e, s, r, 0) CSR order
    const int*   __restrict__ offsets,   // [N_NUC+1]
    const float* __restrict__ ln_scale,
    const float* __restrict__ ln_bias,
    const float* __restrict__ W_e,       // [MSG][MSG]
    float*       __restrict__ msg)       // [N_NUC][MSG], pre-zeroed
{
    __shared__ unsigned lds_ev[256 * LDS_USTR];  // bf16 ev rows -> reused for msg staging
    __shared__ unsigned lds_g [256 * LDS_USTR];  // bf16 gate rows
    __shared__ int      lds_r[256];
    __shared__ int      lds_e[256];

    const int t    = threadIdx.x;
    const int lane = t & 63;
    const int wb   = t & ~63;            // wave's first row (0,64,128,192)
    const int B0   = blockIdx.x * 256;   // first CSR slot of this block

    const int4 pk = edge_pack[B0 + t];
    const int e = pk.x, s = pk.y, r = pk.z;
    lds_r[t] = r;
    lds_e[t] = e;

    // ---- B fragments of W_e (bf16): lane holds k=8*(lane>>4)+i, n=lane&15 ----
    bf16x8 bf0, bf1;
    {
        const int kg = (lane >> 4) * 8;
        const int n0 = lane & 15;
        #pragma unroll
        for (int i = 0; i < 8; ++i) {
            bf0[i] = (short)bf16_of(W_e[(kg + i) * MSG_C + n0]);
            bf1[i] = (short)bf16_of(W_e[(kg + i) * MSG_C + 16 + n0]);
        }
    }

    __syncthreads();   // B0: lds_e ready

    // ---- cooperative e_embed gather: 8 lanes per row, bf16-pack in flight ----
    {
        const int rowb = t >> 3;          // 0..31 (32 rows per pass)
        const int sub  = t & 7;           // 16 B chunk within the row
        #pragma unroll
        for (int p = 0; p < 8; ++p) {
            const int i  = p * 32 + rowb;
            const int ei = lds_e[i];      // broadcast within 8-lane group
            const float4 v = *reinterpret_cast<const float4*>(
                e_embed + (size_t)ei * MSG_C + sub * 4);
            lds_ev[i * LDS_USTR + sub * 2 + 0] = pack_bf16x2(v.x, v.y);
            lds_ev[i * LDS_USTR + sub * 2 + 1] = pack_bf16x2(v.z, v.w);
        }
    }

    __syncthreads();   // B1: all ev rows staged

    // ---- MFMA: gate = ev @ W_e, write bf16 gate rows to LDS ----
    {
        unsigned short* g16 = reinterpret_cast<unsigned short*>(lds_g);
        #pragma unroll
        for (int mt = 0; mt < 4; ++mt) {
            const int arow = wb + mt * 16 + (lane & 15);
            const unsigned* ar = &lds_ev[arow * LDS_USTR + ((lane >> 4) << 2)];
            union { unsigned u[4]; bf16x8 v; } cvt;
            cvt.u[0] = ar[0]; cvt.u[1] = ar[1]; cvt.u[2] = ar[2]; cvt.u[3] = ar[3];
            const bf16x8 af = cvt.v;    // bf16 row already in operand order
            f32x4 z = {0.f, 0.f, 0.f, 0.f};
            const f32x4 a0 = __builtin_amdgcn_mfma_f32_16x16x32_bf16(af, bf0, z, 0, 0, 0);
            const f32x4 a1 = __builtin_amdgcn_mfma_f32_16x16x32_bf16(af, bf1, z, 0, 0, 0);
            const int rbase = wb + mt * 16 + ((lane >> 4) << 2);
            #pragma unroll
            for (int rg = 0; rg < 4; ++rg) {
                g16[(rbase + rg) * (2 * LDS_USTR) + (lane & 15)]      = bf16_of(a0[rg]);
                g16[(rbase + rg) * (2 * LDS_USTR) + 16 + (lane & 15)] = bf16_of(a1[rg]);
            }
        }
    }

    __syncthreads();   // B2: all gate rows written

    // ---- own gate row -> registers ----
    float g[MSG_C];
    {
        const unsigned* gr = &lds_g[t * LDS_USTR];
        #pragma unroll
        for (int j = 0; j < 16; ++j) {
            const unsigned u = gr[j];
            g[2*j]   = __uint_as_float(u << 16);
            g[2*j+1] = __uint_as_float(u & 0xFFFF0000u);
        }
    }

    // ---- x = proj_s + proj_r, LayerNorm + SiLU, msg -> lds_ev (reuse) ----
    const float4* ps = reinterpret_cast<const float4*>(proj + (size_t)s * MSG_C);
    const float4* pq = reinterpret_cast<const float4*>(proj + (size_t)(N_NUC_C + r) * MSG_C);
    float x[MSG_C];
    #pragma unroll
    for (int q = 0; q < 8; ++q) {
        const float4 a = ps[q];
        const float4 b = pq[q];
        x[4*q+0] = a.x + b.x; x[4*q+1] = a.y + b.y;
        x[4*q+2] = a.z + b.z; x[4*q+3] = a.w + b.w;
    }

    float mu = 0.0f;
    #pragma unroll
    for (int c = 0; c < MSG_C; ++c) mu += x[c];
    mu *= (1.0f / MSG_C);
    float var = 0.0f;
    #pragma unroll
    for (int c = 0; c < MSG_C; ++c) { const float d = x[c] - mu; var = fmaf(d, d, var); }
    var *= (1.0f / MSG_C);
    const float rs = rsqrtf(var + 1e-6f);

    unsigned* orow = &lds_ev[t * LDS_USTR];
    #pragma unroll
    for (int i = 0; i < 16; ++i) {
        const int c0_ = 2*i, c1_ = 2*i + 1;
        const float y0 = (x[c0_] - mu) * rs * ln_scale[c0_] + ln_bias[c0_];
        const float y1 = (x[c1_] - mu) * rs * ln_scale[c1_] + ln_bias[c1_];
        orow[i] = pack_bf16x2(silu_f(y0) * g[c0_], silu_f(y1) * g[c1_]);
    }

    __syncthreads();   // B3: all msg rows staged

    // ---- segmented reduction over receivers in this block ----
    const int r0 = lds_r[0];
    const int r1 = lds_r[255];
    const int total = (r1 - r0 + 1) << 5;   // (#receivers) * 32 channels

    for (int p = t; p < total; p += 256) {
        const int n  = r0 + (p >> 5);
        const int ch = p & 31;
        int b  = offsets[n];
        int en = offsets[n + 1];
        const bool interior = (b >= B0) && (en <= B0 + 256);
        if (b < B0) b = B0;
        if (en > B0 + 256) en = B0 + 256;

        const int dw  = ch >> 1;
        const bool hi = (ch & 1);
        float sum = 0.0f;
        for (int q = b - B0; q < en - B0; ++q) {
            const unsigned u = lds_ev[q * LDS_USTR + dw];
            sum += __uint_as_float(hi ? (u & 0xFFFF0000u) : (u << 16));
        }

        float* dst = msg + (size_t)n * MSG_C + ch;
        if (interior)       *dst = sum;          // sole owner (incl. empty = 0)
        else if (en > b)    atomicAdd(dst, sum); // straddling segment part
    }
}

// ---------------------------------------------------------------------------
// Fallback (tiny ws): R1 atomic edge kernel
// ---------------------------------------------------------------------------
__global__ __launch_bounds__(256) void edge_kernel(
    const float* __restrict__ proj, const float* __restrict__ e_embed,
    const int* __restrict__ senders, const int* __restrict__ receivers,
    const float* __restrict__ ln_scale, const float* __restrict__ ln_bias,
    const float* __restrict__ W_e, float* __restrict__ msg)
{
    const int e = blockIdx.x * blockDim.x + threadIdx.x;
    if (e >= N_NN_C) return;
    const int s = senders[e];
    const int r = receivers[e];
    const float4* ps = reinterpret_cast<const float4*>(proj + (size_t)s * MSG_C);
    const float4* pq = reinterpret_cast<const float4*>(proj + (size_t)(N_NUC_C + r) * MSG_C);
    float x[MSG_C];
    #pragma unroll
    for (int q = 0; q < 8; ++q) {
        const float4 a = ps[q];
        const float4 b = pq[q];
        x[4*q+0] = a.x + b.x; x[4*q+1] = a.y + b.y;
        x[4*q+2] = a.z + b.z; x[4*q+3] = a.w + b.w;
    }
    float mu = 0.0f;
    #pragma unroll
    for (int c = 0; c < MSG_C; ++c) mu += x[c];
    mu *= (1.0f / MSG_C);
    float var = 0.0f;
    #pragma unroll
    for (int c = 0; c < MSG_C; ++c) { const float d = x[c] - mu; var = fmaf(d, d, var); }
    var *= (1.0f / MSG_C);
    const float rs = rsqrtf(var + 1e-6f);
    #pragma unroll
    for (int c = 0; c < MSG_C; ++c) {
        const float y = (x[c] - mu) * rs * ln_scale[c] + ln_bias[c];
        x[c] = silu_f(y);
    }
    float ev[MSG_C];
    const float4* ee = reinterpret_cast<const float4*>(e_embed + (size_t)e * MSG_C);
    #pragma unroll
    for (int q = 0; q < 8; ++q) {
        const float4 v = ee[q];
        ev[4*q+0] = v.x; ev[4*q+1] = v.y; ev[4*q+2] = v.z; ev[4*q+3] = v.w;
    }
    float g[MSG_C];
    #pragma unroll
    for (int c = 0; c < MSG_C; ++c) g[c] = 0.0f;
    #pragma unroll
    for (int k = 0; k < MSG_C; ++k) {
        const float ek = ev[k];
        #pragma unroll
        for (int c = 0; c < MSG_C; ++c) g[c] = fmaf(ek, W_e[k * MSG_C + c], g[c]);
    }
    float* mrow = msg + (size_t)r * MSG_C;
    #pragma unroll
    for (int c = 0; c < MSG_C; ++c) atomicAdd(mrow + c, x[c] * g[c]);
}

// ---------------------------------------------------------------------------
// Kernel C: out[n][j] = silu( (msg[n] . W_out[:,j]) * norm[n] )
// ---------------------------------------------------------------------------
__global__ __launch_bounds__(256) void out_kernel(
    const float* __restrict__ msg, const float* __restrict__ norm,
    const float* __restrict__ W_out, float* __restrict__ out)
{
    const int j     = threadIdx.x & (OUT_C - 1);
    const int local = threadIdx.x >> 7;

    float w[MSG_C];
    #pragma unroll
    for (int k = 0; k < MSG_C; ++k) w[k] = W_out[k * OUT_C + j];

    for (int n = blockIdx.x * 2 + local; n < N_NUC_C; n += gridDim.x * 2) {
        const float4* m4 = reinterpret_cast<const float4*>(msg + (size_t)n * MSG_C);
        float acc = 0.0f;
        #pragma unroll
        for (int q = 0; q < 8; ++q) {
            const float4 mv = m4[q];
            acc = fmaf(mv.x, w[4*q+0], acc);
            acc = fmaf(mv.y, w[4*q+1], acc);
            acc = fmaf(mv.z, w[4*q+2], acc);
            acc = fmaf(mv.w, w[4*q+3], acc);
        }
        acc *= norm[n];
        out[(size_t)n * OUT_C + j] = silu_f(acc);
    }
}

extern "C" void kernel_launch(void* const* d_in, const int* in_sizes, int n_in,
                              void* d_out, int out_size, void* d_ws, size_t ws_size,
                              hipStream_t stream) {
    const float* s_embed   = (const float*)d_in[0];
    const float* r_embed   = (const float*)d_in[1];
    const float* e_embed   = (const float*)d_in[2];
    const float* norm      = (const float*)d_in[3];
    const int*   senders   = (const int*)d_in[4];
    const int*   receivers = (const int*)d_in[5];
    const float* W_s       = (const float*)d_in[6];
    const float* b_s       = (const float*)d_in[7];
    const float* W_r       = (const float*)d_in[8];
    const float* b_r       = (const float*)d_in[9];
    const float* ln_scale  = (const float*)d_in[10];
    const float* ln_bias   = (const float*)d_in[11];
    const float* W_e       = (const float*)d_in[12];
    const float* W_out     = (const float*)d_in[13];
    float* out = (float*)d_out;

    char* ws = (char*)d_ws;
    size_t off = 0;
    auto alloc = [&](size_t bytes) { char* p = ws + off; off += (bytes + 255) & ~(size_t)255; return p; };

    float* proj      = (float*)alloc((size_t)2 * N_NUC_C * MSG_C * 4); // 25.6 MB
    float* msg       = (float*)alloc((size_t)N_NUC_C * MSG_C * 4);     // 12.8 MB
    const size_t off_min = off;                                        // 38.4 MB
    int*   cnt       = (int*)  alloc((size_t)N_NUC_C * 4);
    int*   excl      = (int*)  alloc((size_t)N_NUC_C * 4);
    int*   offsets   = (int*)  alloc((size_t)(N_NUC_C + 1) * 4);
    int*   blockTot  = (int*)  alloc(128 * 4);
    int*   blockOff  = (int*)  alloc(128 * 4);
    unsigned char* lrank8 = (unsigned char*)alloc((size_t)N_NN_C);     // 1.6 MB
    unsigned char* cnt2   = (unsigned char*)alloc((size_t)NCH2 * N_NUC_C); // 25.6 MB
    int4*  edge_pack = (int4*) alloc((size_t)N_NN_C * 16);             // 25.6 MB
    const size_t off_full = off;                                       // ~92 MB

    if (off_full <= ws_size) {
        // --- custom msg zero (stream-rate, replaces 115us rocclr fill) +
        //     [proj || LDS-hist CSR build] + chunkscan + offsets scan +
        //     partition scatter + fused MFMA edge/reduce ---
        zero_msg_kernel<<<(MSG_F4 + 255) / 256, 256, 0, stream>>>(
            reinterpret_cast<float4*>(msg));
        proj_hist2_kernel<<<HIST_BLOCKS + PROJ_BLOCKS, 256, 0, stream>>>(
            s_embed, r_embed, W_s, b_s, W_r, b_r, proj, receivers, lrank8, cnt2);
        chunkscan_kernel<<<(N_NUC_C + 255) / 256, 256, 0, stream>>>(cnt2, cnt);
        scan1_kernel<<<NB1, 256, 0, stream>>>(cnt, excl, blockTot);
        scan2_kernel<<<1, 128, 0, stream>>>(blockTot, blockOff);
        scan3_kernel<<<(N_NUC_C + 255) / 256, 256, 0, stream>>>(excl, blockOff, offsets);
        scatter_pack8_kernel<<<NPART * SBLK, 256, 0, stream>>>(
            senders, receivers, lrank8, cnt2, offsets, edge_pack);
        fused_csr_kernel<<<N_NN_C / 256, 256, 0, stream>>>(
            proj, e_embed, edge_pack, offsets, ln_scale, ln_bias, W_e, msg);
    } else if (off_min <= ws_size) {
        // --- fallback: R1 atomic path ---
        dim3 pgrid((N_NUC_C + 255) / 256, 4);
        proj_kernel<<<pgrid, 256, 0, stream>>>(s_embed, r_embed, W_s, b_s, W_r, b_r, proj);
        zero_msg_kernel<<<(MSG_F4 + 255) / 256, 256, 0, stream>>>(
            reinterpret_cast<float4*>(msg));
        edge_kernel<<<(N_NN_C + 255) / 256, 256, 0, stream>>>(
            proj, e_embed, senders, receivers, ln_scale, ln_bias, W_e, msg);
    }

    out_kernel<<<2048, 256, 0, stream>>>(msg, norm, W_out, out);
}

// Round 19
// 295.299 us; speedup vs baseline: 1.2415x; 1.0242x over previous
//
#include <hip/hip_runtime.h>
#include <hip/hip_bf16.h>
#include <math.h>

#define N_NUC_C 100000
#define N_NN_C  1600000
#define EMB_C   128
#define MSG_C   32
#define OUT_C   128
#define NB1     98     // ceil(N_NUC / 1024) for the scan
#define NPART   4
#define R_PER_P (N_NUC_C / NPART)          // 25000 receivers per partition (scatter)
#define SBLK    1568                       // blocks per partition in scatter
#define STHREADS (SBLK * 256)              // 401408 threads per partition
#define LDS_USTR 17                        // uint row stride (16 packed + 1 pad)
#define NCH2    256                        // chunks for histogram CSR build
#define CH2     (N_NN_C / NCH2)            // 6250 edges per chunk
#define CH2_IT  ((CH2 + 255) / 256)        // 25
#define HPART   2                          // receiver partitions in histogram
#define HR      (N_NUC_C / HPART)          // 50000 receivers per hist partition
#define HIST_BLOCKS (NCH2 * HPART)         // 512
#define PROJ_BLOCKS 1564                   // ceil(N_NUC/256) * 4
#define MSG_F4  (N_NUC_C * MSG_C / 4)      // 800000 float4s in msg
#define ZERO_BLOCKS ((MSG_F4 + 255) / 256) // 3125

typedef __attribute__((ext_vector_type(8))) short bf16x8;
typedef __attribute__((ext_vector_type(4))) float f32x4;
typedef unsigned long long u64;

__device__ __forceinline__ float silu_f(float y) {
    return y / (1.0f + __expf(-y));
}

// round-to-nearest-even f32->bf16, packed pair (a -> low 16, b -> high 16)
__device__ __forceinline__ unsigned pack_bf16x2(float a, float b) {
    unsigned ua = __float_as_uint(a); ua += 0x7FFFu + ((ua >> 16) & 1u);
    unsigned ub = __float_as_uint(b); ub += 0x7FFFu + ((ub >> 16) & 1u);
    return (ua >> 16) | (ub & 0xFFFF0000u);
}

__device__ __forceinline__ unsigned short bf16_of(float a) {
    unsigned ua = __float_as_uint(a); ua += 0x7FFFu + ((ua >> 16) & 1u);
    return (unsigned short)(ua >> 16);
}

// ---------------------------------------------------------------------------
// proj body (shared)
// ---------------------------------------------------------------------------
__device__ __forceinline__ void proj_body(
    int n, int pr, int c0,
    const float* __restrict__ s_embed, const float* __restrict__ r_embed,
    const float* __restrict__ W_s, const float* __restrict__ b_s,
    const float* __restrict__ W_r, const float* __restrict__ b_r,
    float* __restrict__ proj)
{
    const float* __restrict__ src = pr ? r_embed : s_embed;
    const float* __restrict__ W   = pr ? W_r : W_s;
    const float* __restrict__ b   = pr ? b_r : b_s;
    float* __restrict__ dst = proj + (size_t)pr * N_NUC_C * MSG_C;

    float acc[16];
    #pragma unroll
    for (int i = 0; i < 16; ++i) acc[i] = b[c0 + i];

    const float* row = src + (size_t)n * EMB_C;
    #pragma unroll 4
    for (int k = 0; k < EMB_C; k += 4) {
        const float4 rv = *reinterpret_cast<const float4*>(row + k);
        #pragma unroll
        for (int i = 0; i < 16; ++i) {
            acc[i] = fmaf(rv.x, W[(k + 0) * MSG_C + c0 + i], acc[i]);
            acc[i] = fmaf(rv.y, W[(k + 1) * MSG_C + c0 + i], acc[i]);
            acc[i] = fmaf(rv.z, W[(k + 2) * MSG_C + c0 + i], acc[i]);
            acc[i] = fmaf(rv.w, W[(k + 3) * MSG_C + c0 + i], acc[i]);
        }
    }

    float4* d = reinterpret_cast<float4*>(dst + (size_t)n * MSG_C + c0);
    d[0] = make_float4(acc[0],  acc[1],  acc[2],  acc[3]);
    d[1] = make_float4(acc[4],  acc[5],  acc[6],  acc[7]);
    d[2] = make_float4(acc[8],  acc[9],  acc[10], acc[11]);
    d[3] = make_float4(acc[12], acc[13], acc[14], acc[15]);
}

// ---------------------------------------------------------------------------
// Combined kernel: LDS-histogram CSR build (zero global atomics) + msg zero
// + proj. (R16-proven hist; zeroing folded in to drop a launch.)
// ---------------------------------------------------------------------------
__global__ __launch_bounds__(256) void proj_hist2_kernel(
    const float* __restrict__ s_embed, const float* __restrict__ r_embed,
    const float* __restrict__ W_s, const float* __restrict__ b_s,
    const float* __restrict__ W_r, const float* __restrict__ b_r,
    float* __restrict__ proj,
    const int* __restrict__ receivers,
    unsigned char* __restrict__ lrank8,   // [N_NN]
    unsigned char* __restrict__ cnt2,     // [NCH2][N_NUC]
    float4* __restrict__ msg4)            // [MSG_F4]
{
    __shared__ unsigned cl[HR / 4];   // 12500 uints = 50 KB, 4 byte-counters each
    const int bid = blockIdx.x;

    if (bid < HIST_BLOCKS) {
        const int c   = bid >> 1;
        const int p   = bid & 1;
        const int rlo = p * HR;

        for (int i = threadIdx.x; i < HR / 4; i += 256) cl[i] = 0;
        __syncthreads();

        const int ebase = c * CH2;
        #pragma unroll 1
        for (int it = 0; it < CH2_IT; ++it) {
            const int el = it * 256 + threadIdx.x;
            if (el < CH2) {
                const int e  = ebase + el;
                const int rr = receivers[e] - rlo;
                if ((unsigned)rr < (unsigned)HR) {
                    const int sh = (rr & 3) * 8;
                    const unsigned old = atomicAdd(&cl[rr >> 2], 1u << sh);
                    lrank8[e] = (unsigned char)((old >> sh) & 0xFFu);
                }
            }
        }
        __syncthreads();

        unsigned* dst = reinterpret_cast<unsigned*>(cnt2 + (size_t)c * N_NUC_C + rlo);
        for (int i = threadIdx.x; i < HR / 4; i += 256) dst[i] = cl[i];
        return;
    }

    if (bid < HIST_BLOCKS + ZERO_BLOCKS) {
        const int i = (bid - HIST_BLOCKS) * 256 + threadIdx.x;
        if (i < MSG_F4) msg4[i] = make_float4(0.f, 0.f, 0.f, 0.f);
        return;
    }

    const int pb  = bid - HIST_BLOCKS - ZERO_BLOCKS;  // 0..PROJ_BLOCKS-1
    const int sub = pb & 3;                           // {s,r} x {col half}
    const int n   = (pb >> 2) * 256 + threadIdx.x;
    if (n >= N_NUC_C) return;
    proj_body(n, sub >> 1, (sub & 1) * 16,
              s_embed, r_embed, W_s, b_s, W_r, b_r, proj);
}

// Standalone proj (fallback path)
__global__ __launch_bounds__(256) void proj_kernel(
    const float* __restrict__ s_embed, const float* __restrict__ r_embed,
    const float* __restrict__ W_s, const float* __restrict__ b_s,
    const float* __restrict__ W_r, const float* __restrict__ b_r,
    float* __restrict__ proj)
{
    const int n = blockIdx.x * blockDim.x + threadIdx.x;
    if (n >= N_NUC_C) return;
    const int sub = blockIdx.y;
    proj_body(n, sub >> 1, (sub & 1) * 16,
              s_embed, r_embed, W_s, b_s, W_r, b_r, proj);
}

__global__ __launch_bounds__(256) void zero_msg_kernel(float4* __restrict__ msg4)
{
    const int i = blockIdx.x * 256 + threadIdx.x;
    if (i < MSG_F4) msg4[i] = make_float4(0.f, 0.f, 0.f, 0.f);
}

// ---------------------------------------------------------------------------
// Per-receiver exclusive scan over NCH2 chunk counts (u8, in place) -> cnt.
// ---------------------------------------------------------------------------
__global__ __launch_bounds__(256) void chunkscan_kernel(
    unsigned char* __restrict__ cnt2, int* __restrict__ cnt)
{
    const int r = blockIdx.x * 256 + threadIdx.x;
    if (r >= N_NUC_C) return;
    int s = 0;
    #pragma unroll 8
    for (int c = 0; c < NCH2; ++c) {
        unsigned char* p = cnt2 + (size_t)c * N_NUC_C + r;
        const int t = *p;
        *p = (unsigned char)s;
        s += t;
    }
    cnt[r] = s;
}

// Exclusive scan of cnt[N_NUC] -> offsets. Three tiny kernels.
__global__ __launch_bounds__(256) void scan1_kernel(
    const int* __restrict__ cnt, int* __restrict__ excl, int* __restrict__ blockTot)
{
    __shared__ int waveTot[4];
    const int t = threadIdx.x, b = blockIdx.x;
    const int lane = t & 63, wid = t >> 6;
    const int base = b * 1024 + t * 4;

    int d0 = (base + 0 < N_NUC_C) ? cnt[base + 0] : 0;
    int d1 = (base + 1 < N_NUC_C) ? cnt[base + 1] : 0;
    int d2 = (base + 2 < N_NUC_C) ? cnt[base + 2] : 0;
    int d3 = (base + 3 < N_NUC_C) ? cnt[base + 3] : 0;
    const int s = d0 + d1 + d2 + d3;

    int incl = s;
    #pragma unroll
    for (int off = 1; off < 64; off <<= 1) {
        int v = __shfl_up(incl, off);
        if (lane >= off) incl += v;
    }
    const int wexcl = incl - s;
    if (lane == 63) waveTot[wid] = incl;
    __syncthreads();
    int wbase = 0;
    for (int w = 0; w < wid; ++w) wbase += waveTot[w];
    const int e0 = wbase + wexcl;

    if (base + 0 < N_NUC_C) excl[base + 0] = e0;
    if (base + 1 < N_NUC_C) excl[base + 1] = e0 + d0;
    if (base + 2 < N_NUC_C) excl[base + 2] = e0 + d0 + d1;
    if (base + 3 < N_NUC_C) excl[base + 3] = e0 + d0 + d1 + d2;
    if (t == 255) blockTot[b] = wbase + incl;
}

__global__ __launch_bounds__(128) void scan2_kernel(
    const int* __restrict__ blockTot, int* __restrict__ blockOff)
{
    __shared__ int sh[128];
    const int t = threadIdx.x;
    const int v = (t < NB1) ? blockTot[t] : 0;
    sh[t] = v;
    __syncthreads();
    #pragma unroll
    for (int off = 1; off < 128; off <<= 1) {
        int x = 0;
        if (t >= off) x = sh[t - off];
        __syncthreads();
        sh[t] += x;
        __syncthreads();
    }
    if (t < NB1) blockOff[t] = sh[t] - v;
}

__global__ __launch_bounds__(256) void scan3_kernel(
    const int* __restrict__ excl, const int* __restrict__ blockOff,
    int* __restrict__ offsets)
{
    const int n = blockIdx.x * blockDim.x + threadIdx.x;
    if (n < N_NUC_C) offsets[n] = excl[n] + blockOff[n >> 10];
    if (n == 0) offsets[N_NUC_C] = N_NN_C;
}

// ---------------------------------------------------------------------------
// Partition-local ATOMIC-FREE scatter (4 partitions), u64 pack:
// pack = e | s<<21 | r<<38  (21+17+17 = 55 bits). 8 B/edge halves write
// bytes and shrinks each partition's active window to 3.2 MB (L2-fit).
// ---------------------------------------------------------------------------
__global__ __launch_bounds__(256) void scatter_pack8_kernel(
    const int* __restrict__ senders, const int* __restrict__ receivers,
    const unsigned char* __restrict__ lrank8,
    const unsigned char* __restrict__ cnt2,
    const int* __restrict__ offsets, u64* __restrict__ edge_pack)
{
    const int p    = blockIdx.x & (NPART - 1);
    const int blk  = blockIdx.x / NPART;              // 0..SBLK-1
    const int base = blk * 256 + threadIdx.x;         // 0..STHREADS-1
    const int rlo  = p * R_PER_P;
    const int rhi  = rlo + R_PER_P;

    #pragma unroll
    for (int k = 0; k < NPART; ++k) {
        const int e = base + k * STHREADS;
        if (e < N_NN_C) {
            const int r = receivers[e];
            if (r >= rlo && r < rhi) {
                const int c   = e / CH2;
                const int dst = offsets[r] + (int)cnt2[(size_t)c * N_NUC_C + r]
                                          + (int)lrank8[e];
                edge_pack[dst] = (u64)e | ((u64)senders[e] << 21) | ((u64)r << 38);
            }
        }
    }
}

// ---------------------------------------------------------------------------
// Fused CSR edge compute + in-block segmented reduction, gate via MFMA,
// cooperative e_embed gather (R15/R16-proven; u64 pack decode).
// ---------------------------------------------------------------------------
__global__ __launch_bounds__(256) void fused_csr_kernel(
    const float* __restrict__ proj,      // [2][N_NUC][MSG]
    const float* __restrict__ e_embed,   // [N_NN][MSG]
    const u64*   __restrict__ edge_pack, // [N_NN] packed (e,s,r) CSR order
    const int*   __restrict__ offsets,   // [N_NUC+1]
    const float* __restrict__ ln_scale,
    const float* __restrict__ ln_bias,
    const float* __restrict__ W_e,       // [MSG][MSG]
    float*       __restrict__ msg)       // [N_NUC][MSG], pre-zeroed
{
    __shared__ unsigned lds_ev[256 * LDS_USTR];  // bf16 ev rows -> reused for msg staging
    __shared__ unsigned lds_g [256 * LDS_USTR];  // bf16 gate rows
    __shared__ int      lds_r[256];
    __shared__ int      lds_e[256];

    const int t    = threadIdx.x;
    const int lane = t & 63;
    const int wb   = t & ~63;            // wave's first row (0,64,128,192)
    const int B0   = blockIdx.x * 256;   // first CSR slot of this block

    const u64 pk = edge_pack[B0 + t];
    const int e = (int)(pk & 0x1FFFFFu);
    const int s = (int)((pk >> 21) & 0x1FFFFu);
    const int r = (int)(pk >> 38);
    lds_r[t] = r;
    lds_e[t] = e;

    // ---- B fragments of W_e (bf16): lane holds k=8*(lane>>4)+i, n=lane&15 ----
    bf16x8 bf0, bf1;
    {
        const int kg = (lane >> 4) * 8;
        const int n0 = lane & 15;
        #pragma unroll
        for (int i = 0; i < 8; ++i) {
            bf0[i] = (short)bf16_of(W_e[(kg + i) * MSG_C + n0]);
            bf1[i] = (short)bf16_of(W_e[(kg + i) * MSG_C + 16 + n0]);
        }
    }

    __syncthreads();   // B0: lds_e ready

    // ---- cooperative e_embed gather: 8 lanes per row, bf16-pack in flight ----
    {
        const int rowb = t >> 3;          // 0..31 (32 rows per pass)
        const int sub  = t & 7;           // 16 B chunk within the row
        #pragma unroll
        for (int p = 0; p < 8; ++p) {
            const int i  = p * 32 + rowb;
            const int ei = lds_e[i];      // broadcast within 8-lane group
            const float4 v = *reinterpret_cast<const float4*>(
                e_embed + (size_t)ei * MSG_C + sub * 4);
            lds_ev[i * LDS_USTR + sub * 2 + 0] = pack_bf16x2(v.x, v.y);
            lds_ev[i * LDS_USTR + sub * 2 + 1] = pack_bf16x2(v.z, v.w);
        }
    }

    __syncthreads();   // B1: all ev rows staged

    // ---- MFMA: gate = ev @ W_e, write bf16 gate rows to LDS ----
    {
        unsigned short* g16 = reinterpret_cast<unsigned short*>(lds_g);
        #pragma unroll
        for (int mt = 0; mt < 4; ++mt) {
            const int arow = wb + mt * 16 + (lane & 15);
            const unsigned* ar = &lds_ev[arow * LDS_USTR + ((lane >> 4) << 2)];
            union { unsigned u[4]; bf16x8 v; } cvt;
            cvt.u[0] = ar[0]; cvt.u[1] = ar[1]; cvt.u[2] = ar[2]; cvt.u[3] = ar[3];
            const bf16x8 af = cvt.v;    // bf16 row already in operand order
            f32x4 z = {0.f, 0.f, 0.f, 0.f};
            const f32x4 a0 = __builtin_amdgcn_mfma_f32_16x16x32_bf16(af, bf0, z, 0, 0, 0);
            const f32x4 a1 = __builtin_amdgcn_mfma_f32_16x16x32_bf16(af, bf1, z, 0, 0, 0);
            const int rbase = wb + mt * 16 + ((lane >> 4) << 2);
            #pragma unroll
            for (int rg = 0; rg < 4; ++rg) {
                g16[(rbase + rg) * (2 * LDS_USTR) + (lane & 15)]      = bf16_of(a0[rg]);
                g16[(rbase + rg) * (2 * LDS_USTR) + 16 + (lane & 15)] = bf16_of(a1[rg]);
            }
        }
    }

    __syncthreads();   // B2: all gate rows written

    // ---- own gate row -> registers ----
    float g[MSG_C];
    {
        const unsigned* gr = &lds_g[t * LDS_USTR];
        #pragma unroll
        for (int j = 0; j < 16; ++j) {
            const unsigned u = gr[j];
            g[2*j]   = __uint_as_float(u << 16);
            g[2*j+1] = __uint_as_float(u & 0xFFFF0000u);
        }
    }

    // ---- x = proj_s + proj_r, LayerNorm + SiLU, msg -> lds_ev (reuse) ----
    const float4* ps = reinterpret_cast<const float4*>(proj + (size_t)s * MSG_C);
    const float4* pq = reinterpret_cast<const float4*>(proj + (size_t)(N_NUC_C + r) * MSG_C);
    float x[MSG_C];
    #pragma unroll
    for (int q = 0; q < 8; ++q) {
        const float4 a = ps[q];
        const float4 b = pq[q];
        x[4*q+0] = a.x + b.x; x[4*q+1] = a.y + b.y;
        x[4*q+2] = a.z + b.z; x[4*q+3] = a.w + b.w;
    }

    float mu = 0.0f;
    #pragma unroll
    for (int c = 0; c < MSG_C; ++c) mu += x[c];
    mu *= (1.0f / MSG_C);
    float var = 0.0f;
    #pragma unroll
    for (int c = 0; c < MSG_C; ++c) { const float d = x[c] - mu; var = fmaf(d, d, var); }
    var *= (1.0f / MSG_C);
    const float rs = rsqrtf(var + 1e-6f);

    unsigned* orow = &lds_ev[t * LDS_USTR];
    #pragma unroll
    for (int i = 0; i < 16; ++i) {
        const int c0_ = 2*i, c1_ = 2*i + 1;
        const float y0 = (x[c0_] - mu) * rs * ln_scale[c0_] + ln_bias[c0_];
        const float y1 = (x[c1_] - mu) * rs * ln_scale[c1_] + ln_bias[c1_];
        orow[i] = pack_bf16x2(silu_f(y0) * g[c0_], silu_f(y1) * g[c1_]);
    }

    __syncthreads();   // B3: all msg rows staged

    // ---- segmented reduction over receivers in this block ----
    const int r0 = lds_r[0];
    const int r1 = lds_r[255];
    const int total = (r1 - r0 + 1) << 5;   // (#receivers) * 32 channels

    for (int p = t; p < total; p += 256) {
        const int n  = r0 + (p >> 5);
        const int ch = p & 31;
        int b  = offsets[n];
        int en = offsets[n + 1];
        const bool interior = (b >= B0) && (en <= B0 + 256);
        if (b < B0) b = B0;
        if (en > B0 + 256) en = B0 + 256;

        const int dw  = ch >> 1;
        const bool hi = (ch & 1);
        float sum = 0.0f;
        for (int q = b - B0; q < en - B0; ++q) {
            const unsigned u = lds_ev[q * LDS_USTR + dw];
            sum += __uint_as_float(hi ? (u & 0xFFFF0000u) : (u << 16));
        }

        float* dst = msg + (size_t)n * MSG_C + ch;
        if (interior)       *dst = sum;          // sole owner (incl. empty = 0)
        else if (en > b)    atomicAdd(dst, sum); // straddling segment part
    }
}

// ---------------------------------------------------------------------------
// Fallback (tiny ws): R1 atomic edge kernel
// ---------------------------------------------------------------------------
__global__ __launch_bounds__(256) void edge_kernel(
    const float* __restrict__ proj, const float* __restrict__ e_embed,
    const int* __restrict__ senders, const int* __restrict__ receivers,
    const float* __restrict__ ln_scale, const float* __restrict__ ln_bias,
    const float* __restrict__ W_e, float* __restrict__ msg)
{
    const int e = blockIdx.x * blockDim.x + threadIdx.x;
    if (e >= N_NN_C) return;
    const int s = senders[e];
    const int r = receivers[e];
    const float4* ps = reinterpret_cast<const float4*>(proj + (size_t)s * MSG_C);
    const float4* pq = reinterpret_cast<const float4*>(proj + (size_t)(N_NUC_C + r) * MSG_C);
    float x[MSG_C];
    #pragma unroll
    for (int q = 0; q < 8; ++q) {
        const float4 a = ps[q];
        const float4 b = pq[q];
        x[4*q+0] = a.x + b.x; x[4*q+1] = a.y + b.y;
        x[4*q+2] = a.z + b.z; x[4*q+3] = a.w + b.w;
    }
    float mu = 0.0f;
    #pragma unroll
    for (int c = 0; c < MSG_C; ++c) mu += x[c];
    mu *= (1.0f / MSG_C);
    float var = 0.0f;
    #pragma unroll
    for (int c = 0; c < MSG_C; ++c) { const float d = x[c] - mu; var = fmaf(d, d, var); }
    var *= (1.0f / MSG_C);
    const float rs = rsqrtf(var + 1e-6f);
    #pragma unroll
    for (int c = 0; c < MSG_C; ++c) {
        const float y = (x[c] - mu) * rs * ln_scale[c] + ln_bias[c];
        x[c] = silu_f(y);
    }
    float ev[MSG_C];
    const float4* ee = reinterpret_cast<const float4*>(e_embed + (size_t)e * MSG_C);
    #pragma unroll
    for (int q = 0; q < 8; ++q) {
        const float4 v = ee[q];
        ev[4*q+0] = v.x; ev[4*q+1] = v.y; ev[4*q+2] = v.z; ev[4*q+3] = v.w;
    }
    float g[MSG_C];
    #pragma unroll
    for (int c = 0; c < MSG_C; ++c) g[c] = 0.0f;
    #pragma unroll
    for (int k = 0; k < MSG_C; ++k) {
        const float ek = ev[k];
        #pragma unroll
        for (int c = 0; c < MSG_C; ++c) g[c] = fmaf(ek, W_e[k * MSG_C + c], g[c]);
    }
    float* mrow = msg + (size_t)r * MSG_C;
    #pragma unroll
    for (int c = 0; c < MSG_C; ++c) atomicAdd(mrow + c, x[c] * g[c]);
}

// ---------------------------------------------------------------------------
// Kernel C: out[n][j] = silu( (msg[n] . W_out[:,j]) * norm[n] )
// ---------------------------------------------------------------------------
__global__ __launch_bounds__(256) void out_kernel(
    const float* __restrict__ msg, const float* __restrict__ norm,
    const float* __restrict__ W_out, float* __restrict__ out)
{
    const int j     = threadIdx.x & (OUT_C - 1);
    const int local = threadIdx.x >> 7;

    float w[MSG_C];
    #pragma unroll
    for (int k = 0; k < MSG_C; ++k) w[k] = W_out[k * OUT_C + j];

    for (int n = blockIdx.x * 2 + local; n < N_NUC_C; n += gridDim.x * 2) {
        const float4* m4 = reinterpret_cast<const float4*>(msg + (size_t)n * MSG_C);
        float acc = 0.0f;
        #pragma unroll
        for (int q = 0; q < 8; ++q) {
            const float4 mv = m4[q];
            acc = fmaf(mv.x, w[4*q+0], acc);
            acc = fmaf(mv.y, w[4*q+1], acc);
            acc = fmaf(mv.z, w[4*q+2], acc);
            acc = fmaf(mv.w, w[4*q+3], acc);
        }
        acc *= norm[n];
        out[(size_t)n * OUT_C + j] = silu_f(acc);
    }
}

extern "C" void kernel_launch(void* const* d_in, const int* in_sizes, int n_in,
                              void* d_out, int out_size, void* d_ws, size_t ws_size,
                              hipStream_t stream) {
    const float* s_embed   = (const float*)d_in[0];
    const float* r_embed   = (const float*)d_in[1];
    const float* e_embed   = (const float*)d_in[2];
    const float* norm      = (const float*)d_in[3];
    const int*   senders   = (const int*)d_in[4];
    const int*   receivers = (const int*)d_in[5];
    const float* W_s       = (const float*)d_in[6];
    const float* b_s       = (const float*)d_in[7];
    const float* W_r       = (const float*)d_in[8];
    const float* b_r       = (const float*)d_in[9];
    const float* ln_scale  = (const float*)d_in[10];
    const float* ln_bias   = (const float*)d_in[11];
    const float* W_e       = (const float*)d_in[12];
    const float* W_out     = (const float*)d_in[13];
    float* out = (float*)d_out;

    char* ws = (char*)d_ws;
    size_t off = 0;
    auto alloc = [&](size_t bytes) { char* p = ws + off; off += (bytes + 255) & ~(size_t)255; return p; };

    float* proj      = (float*)alloc((size_t)2 * N_NUC_C * MSG_C * 4); // 25.6 MB
    float* msg       = (float*)alloc((size_t)N_NUC_C * MSG_C * 4);     // 12.8 MB
    const size_t off_min = off;                                        // 38.4 MB
    int*   cnt       = (int*)  alloc((size_t)N_NUC_C * 4);
    int*   excl      = (int*)  alloc((size_t)N_NUC_C * 4);
    int*   offsets   = (int*)  alloc((size_t)(N_NUC_C + 1) * 4);
    int*   blockTot  = (int*)  alloc(128 * 4);
    int*   blockOff  = (int*)  alloc(128 * 4);
    unsigned char* lrank8 = (unsigned char*)alloc((size_t)N_NN_C);     // 1.6 MB
    unsigned char* cnt2   = (unsigned char*)alloc((size_t)NCH2 * N_NUC_C); // 25.6 MB
    u64*   edge_pack = (u64*) alloc((size_t)N_NN_C * 8);               // 12.8 MB
    const size_t off_full = off;                                       // ~79 MB

    if (off_full <= ws_size) {
        // --- [proj || LDS-hist CSR build || msg zero] + chunkscan + scans +
        //     partition scatter (u64 pack) + fused MFMA edge/reduce ---
        proj_hist2_kernel<<<HIST_BLOCKS + ZERO_BLOCKS + PROJ_BLOCKS, 256, 0, stream>>>(
            s_embed, r_embed, W_s, b_s, W_r, b_r, proj, receivers, lrank8, cnt2,
            reinterpret_cast<float4*>(msg));
        chunkscan_kernel<<<(N_NUC_C + 255) / 256, 256, 0, stream>>>(cnt2, cnt);
        scan1_kernel<<<NB1, 256, 0, stream>>>(cnt, excl, blockTot);
        scan2_kernel<<<1, 128, 0, stream>>>(blockTot, blockOff);
        scan3_kernel<<<(N_NUC_C + 255) / 256, 256, 0, stream>>>(excl, blockOff, offsets);
        scatter_pack8_kernel<<<NPART * SBLK, 256, 0, stream>>>(
            senders, receivers, lrank8, cnt2, offsets, edge_pack);
        fused_csr_kernel<<<N_NN_C / 256, 256, 0, stream>>>(
            proj, e_embed, edge_pack, offsets, ln_scale, ln_bias, W_e, msg);
    } else if (off_min <= ws_size) {
        // --- fallback: R1 atomic path ---
        dim3 pgrid((N_NUC_C + 255) / 256, 4);
        proj_kernel<<<pgrid, 256, 0, stream>>>(s_embed, r_embed, W_s, b_s, W_r, b_r, proj);
        zero_msg_kernel<<<(MSG_F4 + 255) / 256, 256, 0, stream>>>(
            reinterpret_cast<float4*>(msg));
        edge_kernel<<<(N_NN_C + 255) / 256, 256, 0, stream>>>(
            proj, e_embed, senders, receivers, ln_scale, ln_bias, W_e, msg);
    }

    out_kernel<<<2048, 256, 0, stream>>>(msg, norm, W_out, out);
}

// Round 20
// 292.954 us; speedup vs baseline: 1.2515x; 1.0080x over previous
//
#include <hip/hip_runtime.h>
#include <hip/hip_bf16.h>
#include <math.h>

#define N_NUC_C 100000
#define N_NN_C  1600000
#define EMB_C   128
#define MSG_C   32
#define OUT_C   128
#define NB1     98     // ceil(N_NUC / 1024) for the scan
#define NPART   4
#define R_PER_P (N_NUC_C / NPART)          // 25000 receivers per partition (scatter)
#define SBLK    1568                       // blocks per partition in scatter
#define STHREADS (SBLK * 256)              // 401408 threads per partition
#define LDS_USTR 17                        // uint row stride (16 packed + 1 pad)
#define NCH2    256                        // chunks for histogram CSR build
#define CH2     (N_NN_C / NCH2)            // 6250 edges per chunk
#define CH2_IT  ((CH2 + 255) / 256)        // 25
#define HPART   2                          // receiver partitions in histogram
#define HR      (N_NUC_C / HPART)          // 50000 receivers per hist partition
#define HIST_BLOCKS (NCH2 * HPART)         // 512
#define PROJ_BLOCKS 1564                   // ceil(N_NUC/256) * 4
#define MSG_F4  (N_NUC_C * MSG_C / 4)      // 800000 float4s in msg
#define ZERO_BLOCKS ((MSG_F4 + 255) / 256) // 3125

typedef __attribute__((ext_vector_type(8))) short bf16x8;
typedef __attribute__((ext_vector_type(4))) float f32x4;
typedef unsigned long long u64;

__device__ __forceinline__ float silu_f(float y) {
    return y / (1.0f + __expf(-y));
}

// round-to-nearest-even f32->bf16, packed pair (a -> low 16, b -> high 16)
__device__ __forceinline__ unsigned pack_bf16x2(float a, float b) {
    unsigned ua = __float_as_uint(a); ua += 0x7FFFu + ((ua >> 16) & 1u);
    unsigned ub = __float_as_uint(b); ub += 0x7FFFu + ((ub >> 16) & 1u);
    return (ua >> 16) | (ub & 0xFFFF0000u);
}

__device__ __forceinline__ unsigned short bf16_of(float a) {
    unsigned ua = __float_as_uint(a); ua += 0x7FFFu + ((ua >> 16) & 1u);
    return (unsigned short)(ua >> 16);
}

// ---------------------------------------------------------------------------
// proj body (shared)
// ---------------------------------------------------------------------------
__device__ __forceinline__ void proj_body(
    int n, int pr, int c0,
    const float* __restrict__ s_embed, const float* __restrict__ r_embed,
    const float* __restrict__ W_s, const float* __restrict__ b_s,
    const float* __restrict__ W_r, const float* __restrict__ b_r,
    float* __restrict__ proj)
{
    const float* __restrict__ src = pr ? r_embed : s_embed;
    const float* __restrict__ W   = pr ? W_r : W_s;
    const float* __restrict__ b   = pr ? b_r : b_s;
    float* __restrict__ dst = proj + (size_t)pr * N_NUC_C * MSG_C;

    float acc[16];
    #pragma unroll
    for (int i = 0; i < 16; ++i) acc[i] = b[c0 + i];

    const float* row = src + (size_t)n * EMB_C;
    #pragma unroll 4
    for (int k = 0; k < EMB_C; k += 4) {
        const float4 rv = *reinterpret_cast<const float4*>(row + k);
        #pragma unroll
        for (int i = 0; i < 16; ++i) {
            acc[i] = fmaf(rv.x, W[(k + 0) * MSG_C + c0 + i], acc[i]);
            acc[i] = fmaf(rv.y, W[(k + 1) * MSG_C + c0 + i], acc[i]);
            acc[i] = fmaf(rv.z, W[(k + 2) * MSG_C + c0 + i], acc[i]);
            acc[i] = fmaf(rv.w, W[(k + 3) * MSG_C + c0 + i], acc[i]);
        }
    }

    float4* d = reinterpret_cast<float4*>(dst + (size_t)n * MSG_C + c0);
    d[0] = make_float4(acc[0],  acc[1],  acc[2],  acc[3]);
    d[1] = make_float4(acc[4],  acc[5],  acc[6],  acc[7]);
    d[2] = make_float4(acc[8],  acc[9],  acc[10], acc[11]);
    d[3] = make_float4(acc[12], acc[13], acc[14], acc[15]);
}

// ---------------------------------------------------------------------------
// Combined kernel: LDS-histogram CSR build (zero global atomics) + msg zero
// + proj. (R16/R19-proven.)
// ---------------------------------------------------------------------------
__global__ __launch_bounds__(256) void proj_hist2_kernel(
    const float* __restrict__ s_embed, const float* __restrict__ r_embed,
    const float* __restrict__ W_s, const float* __restrict__ b_s,
    const float* __restrict__ W_r, const float* __restrict__ b_r,
    float* __restrict__ proj,
    const int* __restrict__ receivers,
    unsigned char* __restrict__ lrank8,   // [N_NN]
    unsigned char* __restrict__ cnt2,     // [NCH2][N_NUC]
    float4* __restrict__ msg4)            // [MSG_F4]
{
    __shared__ unsigned cl[HR / 4];   // 12500 uints = 50 KB, 4 byte-counters each
    const int bid = blockIdx.x;

    if (bid < HIST_BLOCKS) {
        const int c   = bid >> 1;
        const int p   = bid & 1;
        const int rlo = p * HR;

        for (int i = threadIdx.x; i < HR / 4; i += 256) cl[i] = 0;
        __syncthreads();

        const int ebase = c * CH2;
        #pragma unroll 1
        for (int it = 0; it < CH2_IT; ++it) {
            const int el = it * 256 + threadIdx.x;
            if (el < CH2) {
                const int e  = ebase + el;
                const int rr = receivers[e] - rlo;
                if ((unsigned)rr < (unsigned)HR) {
                    const int sh = (rr & 3) * 8;
                    const unsigned old = atomicAdd(&cl[rr >> 2], 1u << sh);
                    lrank8[e] = (unsigned char)((old >> sh) & 0xFFu);
                }
            }
        }
        __syncthreads();

        unsigned* dst = reinterpret_cast<unsigned*>(cnt2 + (size_t)c * N_NUC_C + rlo);
        for (int i = threadIdx.x; i < HR / 4; i += 256) dst[i] = cl[i];
        return;
    }

    if (bid < HIST_BLOCKS + ZERO_BLOCKS) {
        const int i = (bid - HIST_BLOCKS) * 256 + threadIdx.x;
        if (i < MSG_F4) msg4[i] = make_float4(0.f, 0.f, 0.f, 0.f);
        return;
    }

    const int pb  = bid - HIST_BLOCKS - ZERO_BLOCKS;  // 0..PROJ_BLOCKS-1
    const int sub = pb & 3;                           // {s,r} x {col half}
    const int n   = (pb >> 2) * 256 + threadIdx.x;
    if (n >= N_NUC_C) return;
    proj_body(n, sub >> 1, (sub & 1) * 16,
              s_embed, r_embed, W_s, b_s, W_r, b_r, proj);
}

// Standalone proj (fallback path)
__global__ __launch_bounds__(256) void proj_kernel(
    const float* __restrict__ s_embed, const float* __restrict__ r_embed,
    const float* __restrict__ W_s, const float* __restrict__ b_s,
    const float* __restrict__ W_r, const float* __restrict__ b_r,
    float* __restrict__ proj)
{
    const int n = blockIdx.x * blockDim.x + threadIdx.x;
    if (n >= N_NUC_C) return;
    const int sub = blockIdx.y;
    proj_body(n, sub >> 1, (sub & 1) * 16,
              s_embed, r_embed, W_s, b_s, W_r, b_r, proj);
}

__global__ __launch_bounds__(256) void zero_msg_kernel(float4* __restrict__ msg4)
{
    const int i = blockIdx.x * 256 + threadIdx.x;
    if (i < MSG_F4) msg4[i] = make_float4(0.f, 0.f, 0.f, 0.f);
}

// ---------------------------------------------------------------------------
// Per-receiver exclusive scan over NCH2 chunk counts (u8, in place) -> cnt.
// ---------------------------------------------------------------------------
__global__ __launch_bounds__(256) void chunkscan_kernel(
    unsigned char* __restrict__ cnt2, int* __restrict__ cnt)
{
    const int r = blockIdx.x * 256 + threadIdx.x;
    if (r >= N_NUC_C) return;
    int s = 0;
    #pragma unroll 8
    for (int c = 0; c < NCH2; ++c) {
        unsigned char* p = cnt2 + (size_t)c * N_NUC_C + r;
        const int t = *p;
        *p = (unsigned char)s;
        s += t;
    }
    cnt[r] = s;
}

// Exclusive scan of cnt[N_NUC] -> offsets. Three tiny kernels.
__global__ __launch_bounds__(256) void scan1_kernel(
    const int* __restrict__ cnt, int* __restrict__ excl, int* __restrict__ blockTot)
{
    __shared__ int waveTot[4];
    const int t = threadIdx.x, b = blockIdx.x;
    const int lane = t & 63, wid = t >> 6;
    const int base = b * 1024 + t * 4;

    int d0 = (base + 0 < N_NUC_C) ? cnt[base + 0] : 0;
    int d1 = (base + 1 < N_NUC_C) ? cnt[base + 1] : 0;
    int d2 = (base + 2 < N_NUC_C) ? cnt[base + 2] : 0;
    int d3 = (base + 3 < N_NUC_C) ? cnt[base + 3] : 0;
    const int s = d0 + d1 + d2 + d3;

    int incl = s;
    #pragma unroll
    for (int off = 1; off < 64; off <<= 1) {
        int v = __shfl_up(incl, off);
        if (lane >= off) incl += v;
    }
    const int wexcl = incl - s;
    if (lane == 63) waveTot[wid] = incl;
    __syncthreads();
    int wbase = 0;
    for (int w = 0; w < wid; ++w) wbase += waveTot[w];
    const int e0 = wbase + wexcl;

    if (base + 0 < N_NUC_C) excl[base + 0] = e0;
    if (base + 1 < N_NUC_C) excl[base + 1] = e0 + d0;
    if (base + 2 < N_NUC_C) excl[base + 2] = e0 + d0 + d1;
    if (base + 3 < N_NUC_C) excl[base + 3] = e0 + d0 + d1 + d2;
    if (t == 255) blockTot[b] = wbase + incl;
}

__global__ __launch_bounds__(128) void scan2_kernel(
    const int* __restrict__ blockTot, int* __restrict__ blockOff)
{
    __shared__ int sh[128];
    const int t = threadIdx.x;
    const int v = (t < NB1) ? blockTot[t] : 0;
    sh[t] = v;
    __syncthreads();
    #pragma unroll
    for (int off = 1; off < 128; off <<= 1) {
        int x = 0;
        if (t >= off) x = sh[t - off];
        __syncthreads();
        sh[t] += x;
        __syncthreads();
    }
    if (t < NB1) blockOff[t] = sh[t] - v;
}

__global__ __launch_bounds__(256) void scan3_kernel(
    const int* __restrict__ excl, const int* __restrict__ blockOff,
    int* __restrict__ offsets)
{
    const int n = blockIdx.x * blockDim.x + threadIdx.x;
    if (n < N_NUC_C) offsets[n] = excl[n] + blockOff[n >> 10];
    if (n == 0) offsets[N_NUC_C] = N_NN_C;
}

// ---------------------------------------------------------------------------
// Partition-local ATOMIC-FREE scatter (4 partitions), u64 pack:
// pack = e | s<<21 | r<<38  (55 bits).
// ---------------------------------------------------------------------------
__global__ __launch_bounds__(256) void scatter_pack8_kernel(
    const int* __restrict__ senders, const int* __restrict__ receivers,
    const unsigned char* __restrict__ lrank8,
    const unsigned char* __restrict__ cnt2,
    const int* __restrict__ offsets, u64* __restrict__ edge_pack)
{
    const int p    = blockIdx.x & (NPART - 1);
    const int blk  = blockIdx.x / NPART;              // 0..SBLK-1
    const int base = blk * 256 + threadIdx.x;         // 0..STHREADS-1
    const int rlo  = p * R_PER_P;
    const int rhi  = rlo + R_PER_P;

    #pragma unroll
    for (int k = 0; k < NPART; ++k) {
        const int e = base + k * STHREADS;
        if (e < N_NN_C) {
            const int r = receivers[e];
            if (r >= rlo && r < rhi) {
                const int c   = e / CH2;
                const int dst = offsets[r] + (int)cnt2[(size_t)c * N_NUC_C + r]
                                          + (int)lrank8[e];
                edge_pack[dst] = (u64)e | ((u64)senders[e] << 21) | ((u64)r << 38);
            }
        }
    }
}

// ---------------------------------------------------------------------------
// Fused CSR edge compute + in-block segmented reduction, gate via MFMA,
// cooperative e_embed gather. NEW: single LDS buffer — the MFMA phase is
// wave-band-local (wave w reads A-fragments from and writes gate rows to
// rows wb..wb+63 only; in-wave dep chain orders read-before-write), so the
// gate is written back into lds_ev in place, and each thread's msg row
// later overwrites its own gate row (same thread, same addresses).
// LDS 36.9 -> 19.5 KB => occupancy 4 -> ~6 blocks/CU.
// ---------------------------------------------------------------------------
__global__ __launch_bounds__(256) void fused_csr_kernel(
    const float* __restrict__ proj,      // [2][N_NUC][MSG]
    const float* __restrict__ e_embed,   // [N_NN][MSG]
    const u64*   __restrict__ edge_pack, // [N_NN] packed (e,s,r) CSR order
    const int*   __restrict__ offsets,   // [N_NUC+1]
    const float* __restrict__ ln_scale,
    const float* __restrict__ ln_bias,
    const float* __restrict__ W_e,       // [MSG][MSG]
    float*       __restrict__ msg)       // [N_NUC][MSG], pre-zeroed
{
    __shared__ unsigned lds_ev[256 * LDS_USTR];  // ev rows -> gate rows -> msg rows
    __shared__ int      lds_r[256];
    __shared__ int      lds_e[256];

    const int t    = threadIdx.x;
    const int lane = t & 63;
    const int wb   = t & ~63;            // wave's first row (0,64,128,192)
    const int B0   = blockIdx.x * 256;   // first CSR slot of this block

    const u64 pk = edge_pack[B0 + t];
    const int e = (int)(pk & 0x1FFFFFu);
    const int s = (int)((pk >> 21) & 0x1FFFFu);
    const int r = (int)(pk >> 38);
    lds_r[t] = r;
    lds_e[t] = e;

    // ---- B fragments of W_e (bf16): lane holds k=8*(lane>>4)+i, n=lane&15 ----
    bf16x8 bf0, bf1;
    {
        const int kg = (lane >> 4) * 8;
        const int n0 = lane & 15;
        #pragma unroll
        for (int i = 0; i < 8; ++i) {
            bf0[i] = (short)bf16_of(W_e[(kg + i) * MSG_C + n0]);
            bf1[i] = (short)bf16_of(W_e[(kg + i) * MSG_C + 16 + n0]);
        }
    }

    __syncthreads();   // B0: lds_e ready

    // ---- cooperative e_embed gather: 8 lanes per row, bf16-pack in flight ----
    {
        const int rowb = t >> 3;          // 0..31 (32 rows per pass)
        const int sub  = t & 7;           // 16 B chunk within the row
        #pragma unroll
        for (int p = 0; p < 8; ++p) {
            const int i  = p * 32 + rowb;
            const int ei = lds_e[i];      // broadcast within 8-lane group
            const float4 v = *reinterpret_cast<const float4*>(
                e_embed + (size_t)ei * MSG_C + sub * 4);
            lds_ev[i * LDS_USTR + sub * 2 + 0] = pack_bf16x2(v.x, v.y);
            lds_ev[i * LDS_USTR + sub * 2 + 1] = pack_bf16x2(v.z, v.w);
        }
    }

    __syncthreads();   // B1: all ev rows staged

    // ---- MFMA: gate = ev @ W_e, in place within the wave's 64-row band ----
    {
        // load all 4 A fragments first (reads precede writes via dep chain)
        union { unsigned u[4]; bf16x8 v; } c0_, c1_, c2_, c3_;
        {
            const int col = (lane >> 4) << 2;
            const unsigned* a0 = &lds_ev[(wb +  0 + (lane & 15)) * LDS_USTR + col];
            const unsigned* a1 = &lds_ev[(wb + 16 + (lane & 15)) * LDS_USTR + col];
            const unsigned* a2 = &lds_ev[(wb + 32 + (lane & 15)) * LDS_USTR + col];
            const unsigned* a3 = &lds_ev[(wb + 48 + (lane & 15)) * LDS_USTR + col];
            #pragma unroll
            for (int j = 0; j < 4; ++j) { c0_.u[j] = a0[j]; c1_.u[j] = a1[j]; c2_.u[j] = a2[j]; c3_.u[j] = a3[j]; }
        }
        unsigned short* g16 = reinterpret_cast<unsigned short*>(lds_ev);
        const f32x4 z = {0.f, 0.f, 0.f, 0.f};
        #pragma unroll
        for (int mt = 0; mt < 4; ++mt) {
            const bf16x8 af = (mt == 0) ? c0_.v : (mt == 1) ? c1_.v : (mt == 2) ? c2_.v : c3_.v;
            const f32x4 a0 = __builtin_amdgcn_mfma_f32_16x16x32_bf16(af, bf0, z, 0, 0, 0);
            const f32x4 a1 = __builtin_amdgcn_mfma_f32_16x16x32_bf16(af, bf1, z, 0, 0, 0);
            const int rbase = wb + mt * 16 + ((lane >> 4) << 2);
            #pragma unroll
            for (int rg = 0; rg < 4; ++rg) {
                g16[(rbase + rg) * (2 * LDS_USTR) + (lane & 15)]      = bf16_of(a0[rg]);
                g16[(rbase + rg) * (2 * LDS_USTR) + 16 + (lane & 15)] = bf16_of(a1[rg]);
            }
        }
    }

    __syncthreads();   // B2: all gate rows written

    // ---- own gate row -> registers ----
    float g[MSG_C];
    {
        const unsigned* gr = &lds_ev[t * LDS_USTR];
        #pragma unroll
        for (int j = 0; j < 16; ++j) {
            const unsigned u = gr[j];
            g[2*j]   = __uint_as_float(u << 16);
            g[2*j+1] = __uint_as_float(u & 0xFFFF0000u);
        }
    }

    // ---- x = proj_s + proj_r, LayerNorm + SiLU, msg -> own row (reuse) ----
    const float4* ps = reinterpret_cast<const float4*>(proj + (size_t)s * MSG_C);
    const float4* pq = reinterpret_cast<const float4*>(proj + (size_t)(N_NUC_C + r) * MSG_C);
    float x[MSG_C];
    #pragma unroll
    for (int q = 0; q < 8; ++q) {
        const float4 a = ps[q];
        const float4 b = pq[q];
        x[4*q+0] = a.x + b.x; x[4*q+1] = a.y + b.y;
        x[4*q+2] = a.z + b.z; x[4*q+3] = a.w + b.w;
    }

    float mu = 0.0f;
    #pragma unroll
    for (int c = 0; c < MSG_C; ++c) mu += x[c];
    mu *= (1.0f / MSG_C);
    float var = 0.0f;
    #pragma unroll
    for (int c = 0; c < MSG_C; ++c) { const float d = x[c] - mu; var = fmaf(d, d, var); }
    var *= (1.0f / MSG_C);
    const float rs = rsqrtf(var + 1e-6f);

    unsigned* orow = &lds_ev[t * LDS_USTR];   // same thread, same addresses as gate read
    #pragma unroll
    for (int i = 0; i < 16; ++i) {
        const int c0_ = 2*i, c1_ = 2*i + 1;
        const float y0 = (x[c0_] - mu) * rs * ln_scale[c0_] + ln_bias[c0_];
        const float y1 = (x[c1_] - mu) * rs * ln_scale[c1_] + ln_bias[c1_];
        orow[i] = pack_bf16x2(silu_f(y0) * g[c0_], silu_f(y1) * g[c1_]);
    }

    __syncthreads();   // B3: all msg rows staged

    // ---- segmented reduction over receivers in this block ----
    const int r0 = lds_r[0];
    const int r1 = lds_r[255];
    const int total = (r1 - r0 + 1) << 5;   // (#receivers) * 32 channels

    for (int p = t; p < total; p += 256) {
        const int n  = r0 + (p >> 5);
        const int ch = p & 31;
        int b  = offsets[n];
        int en = offsets[n + 1];
        const bool interior = (b >= B0) && (en <= B0 + 256);
        if (b < B0) b = B0;
        if (en > B0 + 256) en = B0 + 256;

        const int dw  = ch >> 1;
        const bool hi = (ch & 1);
        float sum = 0.0f;
        for (int q = b - B0; q < en - B0; ++q) {
            const unsigned u = lds_ev[q * LDS_USTR + dw];
            sum += __uint_as_float(hi ? (u & 0xFFFF0000u) : (u << 16));
        }

        float* dst = msg + (size_t)n * MSG_C + ch;
        if (interior)       *dst = sum;          // sole owner (incl. empty = 0)
        else if (en > b)    atomicAdd(dst, sum); // straddling segment part
    }
}

// ---------------------------------------------------------------------------
// Fallback (tiny ws): R1 atomic edge kernel
// ---------------------------------------------------------------------------
__global__ __launch_bounds__(256) void edge_kernel(
    const float* __restrict__ proj, const float* __restrict__ e_embed,
    const int* __restrict__ senders, const int* __restrict__ receivers,
    const float* __restrict__ ln_scale, const float* __restrict__ ln_bias,
    const float* __restrict__ W_e, float* __restrict__ msg)
{
    const int e = blockIdx.x * blockDim.x + threadIdx.x;
    if (e >= N_NN_C) return;
    const int s = senders[e];
    const int r = receivers[e];
    const float4* ps = reinterpret_cast<const float4*>(proj + (size_t)s * MSG_C);
    const float4* pq = reinterpret_cast<const float4*>(proj + (size_t)(N_NUC_C + r) * MSG_C);
    float x[MSG_C];
    #pragma unroll
    for (int q = 0; q < 8; ++q) {
        const float4 a = ps[q];
        const float4 b = pq[q];
        x[4*q+0] = a.x + b.x; x[4*q+1] = a.y + b.y;
        x[4*q+2] = a.z + b.z; x[4*q+3] = a.w + b.w;
    }
    float mu = 0.0f;
    #pragma unroll
    for (int c = 0; c < MSG_C; ++c) mu += x[c];
    mu *= (1.0f / MSG_C);
    float var = 0.0f;
    #pragma unroll
    for (int c = 0; c < MSG_C; ++c) { const float d = x[c] - mu; var = fmaf(d, d, var); }
    var *= (1.0f / MSG_C);
    const float rs = rsqrtf(var + 1e-6f);
    #pragma unroll
    for (int c = 0; c < MSG_C; ++c) {
        const float y = (x[c] - mu) * rs * ln_scale[c] + ln_bias[c];
        x[c] = silu_f(y);
    }
    float ev[MSG_C];
    const float4* ee = reinterpret_cast<const float4*>(e_embed + (size_t)e * MSG_C);
    #pragma unroll
    for (int q = 0; q < 8; ++q) {
        const float4 v = ee[q];
        ev[4*q+0] = v.x; ev[4*q+1] = v.y; ev[4*q+2] = v.z; ev[4*q+3] = v.w;
    }
    float g[MSG_C];
    #pragma unroll
    for (int c = 0; c < MSG_C; ++c) g[c] = 0.0f;
    #pragma unroll
    for (int k = 0; k < MSG_C; ++k) {
        const float ek = ev[k];
        #pragma unroll
        for (int c = 0; c < MSG_C; ++c) g[c] = fmaf(ek, W_e[k * MSG_C + c], g[c]);
    }
    float* mrow = msg + (size_t)r * MSG_C;
    #pragma unroll
    for (int c = 0; c < MSG_C; ++c) atomicAdd(mrow + c, x[c] * g[c]);
}

// ---------------------------------------------------------------------------
// Kernel C: out[n][j] = silu( (msg[n] . W_out[:,j]) * norm[n] )
// ---------------------------------------------------------------------------
__global__ __launch_bounds__(256) void out_kernel(
    const float* __restrict__ msg, const float* __restrict__ norm,
    const float* __restrict__ W_out, float* __restrict__ out)
{
    const int j     = threadIdx.x & (OUT_C - 1);
    const int local = threadIdx.x >> 7;

    float w[MSG_C];
    #pragma unroll
    for (int k = 0; k < MSG_C; ++k) w[k] = W_out[k * OUT_C + j];

    for (int n = blockIdx.x * 2 + local; n < N_NUC_C; n += gridDim.x * 2) {
        const float4* m4 = reinterpret_cast<const float4*>(msg + (size_t)n * MSG_C);
        float acc = 0.0f;
        #pragma unroll
        for (int q = 0; q < 8; ++q) {
            const float4 mv = m4[q];
            acc = fmaf(mv.x, w[4*q+0], acc);
            acc = fmaf(mv.y, w[4*q+1], acc);
            acc = fmaf(mv.z, w[4*q+2], acc);
            acc = fmaf(mv.w, w[4*q+3], acc);
        }
        acc *= norm[n];
        out[(size_t)n * OUT_C + j] = silu_f(acc);
    }
}

extern "C" void kernel_launch(void* const* d_in, const int* in_sizes, int n_in,
                              void* d_out, int out_size, void* d_ws, size_t ws_size,
                              hipStream_t stream) {
    const float* s_embed   = (const float*)d_in[0];
    const float* r_embed   = (const float*)d_in[1];
    const float* e_embed   = (const float*)d_in[2];
    const float* norm      = (const float*)d_in[3];
    const int*   senders   = (const int*)d_in[4];
    const int*   receivers = (const int*)d_in[5];
    const float* W_s       = (const float*)d_in[6];
    const float* b_s       = (const float*)d_in[7];
    const float* W_r       = (const float*)d_in[8];
    const float* b_r       = (const float*)d_in[9];
    const float* ln_scale  = (const float*)d_in[10];
    const float* ln_bias   = (const float*)d_in[11];
    const float* W_e       = (const float*)d_in[12];
    const float* W_out     = (const float*)d_in[13];
    float* out = (float*)d_out;

    char* ws = (char*)d_ws;
    size_t off = 0;
    auto alloc = [&](size_t bytes) { char* p = ws + off; off += (bytes + 255) & ~(size_t)255; return p; };

    float* proj      = (float*)alloc((size_t)2 * N_NUC_C * MSG_C * 4); // 25.6 MB
    float* msg       = (float*)alloc((size_t)N_NUC_C * MSG_C * 4);     // 12.8 MB
    const size_t off_min = off;                                        // 38.4 MB
    int*   cnt       = (int*)  alloc((size_t)N_NUC_C * 4);
    int*   excl      = (int*)  alloc((size_t)N_NUC_C * 4);
    int*   offsets   = (int*)  alloc((size_t)(N_NUC_C + 1) * 4);
    int*   blockTot  = (int*)  alloc(128 * 4);
    int*   blockOff  = (int*)  alloc(128 * 4);
    unsigned char* lrank8 = (unsigned char*)alloc((size_t)N_NN_C);     // 1.6 MB
    unsigned char* cnt2   = (unsigned char*)alloc((size_t)NCH2 * N_NUC_C); // 25.6 MB
    u64*   edge_pack = (u64*) alloc((size_t)N_NN_C * 8);               // 12.8 MB
    const size_t off_full = off;                                       // ~79 MB

    if (off_full <= ws_size) {
        // --- [proj || LDS-hist CSR build || msg zero] + chunkscan + scans +
        //     partition scatter (u64 pack) + fused MFMA edge/reduce ---
        proj_hist2_kernel<<<HIST_BLOCKS + ZERO_BLOCKS + PROJ_BLOCKS, 256, 0, stream>>>(
            s_embed, r_embed, W_s, b_s, W_r, b_r, proj, receivers, lrank8, cnt2,
            reinterpret_cast<float4*>(msg));
        chunkscan_kernel<<<(N_NUC_C + 255) / 256, 256, 0, stream>>>(cnt2, cnt);
        scan1_kernel<<<NB1, 256, 0, stream>>>(cnt, excl, blockTot);
        scan2_kernel<<<1, 128, 0, stream>>>(blockTot, blockOff);
        scan3_kernel<<<(N_NUC_C + 255) / 256, 256, 0, stream>>>(excl, blockOff, offsets);
        scatter_pack8_kernel<<<NPART * SBLK, 256, 0, stream>>>(
            senders, receivers, lrank8, cnt2, offsets, edge_pack);
        fused_csr_kernel<<<N_NN_C / 256, 256, 0, stream>>>(
            proj, e_embed, edge_pack, offsets, ln_scale, ln_bias, W_e, msg);
    } else if (off_min <= ws_size) {
        // --- fallback: R1 atomic path ---
        dim3 pgrid((N_NUC_C + 255) / 256, 4);
        proj_kernel<<<pgrid, 256, 0, stream>>>(s_embed, r_embed, W_s, b_s, W_r, b_r, proj);
        zero_msg_kernel<<<(MSG_F4 + 255) / 256, 256, 0, stream>>>(
            reinterpret_cast<float4*>(msg));
        edge_kernel<<<(N_NN_C + 255) / 256, 256, 0, stream>>>(
            proj, e_embed, senders, receivers, ln_scale, ln_bias, W_e, msg);
    }

    out_kernel<<<2048, 256, 0, stream>>>(msg, norm, W_out, out);
}